// Round 1
// baseline (3140.232 us; speedup 1.0000x reference)
//
#include <hip/hip_runtime.h>
#include <math.h>

// ---------------------------------------------------------------------------
// GATr forward on MI355X. B=4, N=4096, H=5, BLK=3, INV=32, 16 blades.
// Metric (0,1,1,1) PGA. Blade order sorted by (grade, mask).
// ---------------------------------------------------------------------------

namespace ga {
constexpr int MASKS[16] = {0,1,2,4,8,3,5,6,9,10,12,7,11,13,14,15};
constexpr int popc4(int x){ return (x&1)+((x>>1)&1)+((x>>2)&1)+((x>>3)&1); }
constexpr int idx_of(int m){ int r=-1; for(int i=0;i<16;i++) if(MASKS[i]==m) r=i; return r; }
struct GPTab {
  int cnt[16];
  signed char ii[16][16];
  signed char jj[16][16];
  float ss[16][16];
};
constexpr GPTab make_gptab(){
  GPTab t{};
  for(int i=0;i<16;i++) for(int j=0;j<16;j++){
    int a=MASKS[i], b=MASKS[j];
    if((a&b&1)!=0) continue;           // e0^2 = 0 kills the term
    int sw=0;
    for(int bi=0;bi<4;bi++) if((b>>bi)&1) sw += popc4(a>>(bi+1));
    int k = idx_of(a^b);
    int c = t.cnt[k];
    t.ii[k][c]=(signed char)i; t.jj[k][c]=(signed char)j;
    t.ss[k][c]=(sw&1)? -1.0f : 1.0f;
    t.cnt[k]=c+1;
  }
  return t;
}
} // namespace ga

__device__ const ga::GPTab GPT = ga::make_gptab();
__constant__ int GRADE16[16] = {0,1,1,1,1,2,2,2,2,2,2,3,3,3,3,4};
// blades with INNER==1: idx {0,2,3,4,7,9,10,14} -> mask 0x469D; compressed pos:
__constant__ int CPOS16[16] = {0,-1,1,2,3,-1,-1,4,-1,5,6,-1,-1,-1,7,-1};

#define NTOK 16384   // B*N
#define NSEQ 4096
#define NB 4

// --------------------------------------------------------------------------
// K1: h[token][o][c] = equi_linear(mv, w_in); mv sparse: ch0 = {1, vec@5,6,8},
// ch1..31 scalar-only.
// --------------------------------------------------------------------------
__global__ __launch_bounds__(256) void k_init_h(
    const float* __restrict__ x, const float* __restrict__ w_in,
    float* __restrict__ h)
{
  int gid = blockIdx.x*256 + threadIdx.x;      // token*5 + o
  if (gid >= NTOK*5) return;
  int o = gid % 5, token = gid / 5;
  const float* xt = x + (size_t)token*35;
  const float* w0 = w_in + o*32;               // grade-0 block, row o
  float s = w0[0];                             // mv[0][0] = 1.0
  #pragma unroll
  for (int i=1;i<32;i++) s += w0[i]*xt[i];
  float w2c = w_in[2*160 + o*32 + 0];          // grade-2, input channel 0
  float* ht = h + (size_t)token*80 + o*16;
  #pragma unroll
  for (int c=0;c<16;c++) ht[c] = 0.f;
  ht[0] = s;
  ht[5] = w2c*xt[32];
  ht[6] = w2c*xt[33];
  ht[8] = w2c*xt[34];
}

// --------------------------------------------------------------------------
// K2: fused equi_layernorm + q,k,v equi_linear. 16 threads per token (one per
// blade), 16 tokens per 256-thread block. q/k stored compressed (40 feats),
// q pre-scaled by 1/sqrt(80). v stored full (80).
// --------------------------------------------------------------------------
__global__ __launch_bounds__(256) void k_ln_qkv(
    const float* __restrict__ h,
    const float* __restrict__ wq, const float* __restrict__ wk,
    const float* __restrict__ wv,
    float* __restrict__ qf, float* __restrict__ kf, float* __restrict__ vf)
{
  int tid = threadIdx.x;
  int c   = tid & 15;
  int token = blockIdx.x*16 + (tid>>4);
  const float* ht = h + (size_t)token*80;
  float hv[5];
  #pragma unroll
  for (int i=0;i<5;i++) hv[i] = ht[i*16 + c];
  bool inner = (0x469D >> c) & 1;
  float part = 0.f;
  if (inner) {
    #pragma unroll
    for (int i=0;i<5;i++) part += hv[i]*hv[i];
  }
  part += __shfl_xor(part, 1);
  part += __shfl_xor(part, 2);
  part += __shfl_xor(part, 4);
  part += __shfl_xor(part, 8);
  float denom = sqrtf(part*(1.f/80.f) + 1e-6f);
  float rinv = 1.f/denom;
  float rln[5];
  #pragma unroll
  for (int i=0;i<5;i++) rln[i] = hv[i]*rinv;

  int g = GRADE16[c];
  int cp = CPOS16[c];
  const float scale = 0.11180339887498949f;    // 1/sqrt(16*5)
  #pragma unroll
  for (int o=0;o<5;o++) {
    const float* wqr = wq + g*25 + o*5;
    const float* wkr = wk + g*25 + o*5;
    const float* wvr = wv + g*25 + o*5;
    float aq=0.f, ak=0.f, av=0.f;
    #pragma unroll
    for (int i=0;i<5;i++) {
      aq += rln[i]*wqr[i];
      ak += rln[i]*wkr[i];
      av += rln[i]*wvr[i];
    }
    vf[(size_t)token*80 + o*16 + c] = av;
    if (inner) {
      qf[(size_t)token*40 + o*8 + cp] = aq*scale;
      kf[(size_t)token*40 + o*8 + cp] = ak;
    }
  }
}

// --------------------------------------------------------------------------
// K3: flash attention + out-projection + residual. Grid (N/32, B), 256 thr.
// 8 lanes per row: lane sub owns 5 of the 40 logit feats and 10 of the 80 v
// dims. Online softmax, exact branch-rescale. K/V tiles (64 keys) in LDS.
// --------------------------------------------------------------------------
__global__ __launch_bounds__(256) void k_attn(
    const float* __restrict__ qf, const float* __restrict__ kf,
    const float* __restrict__ vf, const float* __restrict__ wo,
    float* __restrict__ h)
{
  __shared__ float sk[64*40];   // 10.24 KB
  __shared__ float sv[64*80];   // 20.48 KB
  int tid = threadIdx.x;
  int sub = tid & 7;            // feature slice
  int r   = tid >> 3;           // 0..31 row within block
  int b   = blockIdx.y;
  int row = blockIdx.x*32 + r;
  int token = b*NSEQ + row;

  float q5[5];
  const float* qp = qf + (size_t)token*40 + sub*5;
  #pragma unroll
  for (int f=0;f<5;f++) q5[f]=qp[f];

  float acc[10];
  #pragma unroll
  for (int j=0;j<10;j++) acc[j]=0.f;
  float m = -1e30f, l = 0.f;

  for (int t0=0; t0<NSEQ; t0+=64) {
    __syncthreads();
    const float4* ks = (const float4*)(kf + ((size_t)b*NSEQ + t0)*40);
    float4* sk4 = (float4*)sk;
    for (int i=tid;i<640;i+=256) sk4[i]=ks[i];
    const float4* vs = (const float4*)(vf + ((size_t)b*NSEQ + t0)*80);
    float4* sv4 = (float4*)sv;
    for (int i=tid;i<1280;i+=256) sv4[i]=vs[i];
    __syncthreads();
    for (int kk=0;kk<64;kk++) {
      const float* kr = sk + kk*40 + sub*5;
      float lg = 0.f;
      #pragma unroll
      for (int f=0;f<5;f++) lg += q5[f]*kr[f];
      lg += __shfl_xor(lg,1);
      lg += __shfl_xor(lg,2);
      lg += __shfl_xor(lg,4);    // all 8 lanes: full 40-dim logit
      float p;
      if (lg <= m) {
        p = __expf(lg - m);
      } else {                   // new max: rescale (rare after warmup)
        float rs = __expf(m - lg);
        #pragma unroll
        for (int j=0;j<10;j++) acc[j]*=rs;
        l *= rs; m = lg; p = 1.f;
      }
      l += p;
      const float* vr = sv + kk*80 + sub*10;
      #pragma unroll
      for (int j=0;j<10;j++) acc[j] += p*vr[j];
    }
  }
  __syncthreads();
  // write normalized attention output rows into sk (32*80 = 2560 floats)
  float invl = 1.f/l;
  #pragma unroll
  for (int j=0;j<10;j++) sk[r*80 + sub*10 + j] = acc[j]*invl;
  __syncthreads();
  // out-projection (equi_linear with wo) + residual into h
  for (int idx=tid; idx<32*80; idx+=256) {
    int rr = idx/80, oc = idx%80;
    int o = oc>>4, c = oc&15;
    int g = GRADE16[c];
    const float* wor = wo + g*25 + o*5;
    float a = 0.f;
    #pragma unroll
    for (int i=0;i<5;i++) a += sk[rr*80 + i*16 + c]*wor[i];
    int tok2 = b*NSEQ + blockIdx.x*32 + rr;
    h[(size_t)tok2*80 + oc] += a;
  }
}

// --------------------------------------------------------------------------
// K4: fused equi_layernorm + MLP (w1 -> geometric product -> gated gelu ->
// w2) + residual. 16 threads/token (one per output blade), 16 tokens/block.
// --------------------------------------------------------------------------
__global__ __launch_bounds__(256) void k_mlp(
    float* __restrict__ h,
    const float* __restrict__ w1, const float* __restrict__ w2)
{
  __shared__ float sh1[16][10][16];
  int tid = threadIdx.x;
  int c   = tid & 15;
  int tl  = tid >> 4;
  int token = blockIdx.x*16 + tl;
  float* ht = h + (size_t)token*80;
  float hv[5];
  #pragma unroll
  for (int i=0;i<5;i++) hv[i] = ht[i*16 + c];
  bool inner = (0x469D >> c) & 1;
  float part = 0.f;
  if (inner) {
    #pragma unroll
    for (int i=0;i<5;i++) part += hv[i]*hv[i];
  }
  part += __shfl_xor(part, 1);
  part += __shfl_xor(part, 2);
  part += __shfl_xor(part, 4);
  part += __shfl_xor(part, 8);
  float denom = sqrtf(part*(1.f/80.f) + 1e-6f);
  float rinv = 1.f/denom;
  float rln[5];
  #pragma unroll
  for (int i=0;i<5;i++) rln[i] = hv[i]*rinv;

  int g = GRADE16[c];
  #pragma unroll
  for (int o=0;o<10;o++) {
    const float* w1r = w1 + g*50 + o*5;
    float a=0.f;
    #pragma unroll
    for (int i=0;i<5;i++) a += rln[i]*w1r[i];
    sh1[tl][o][c] = a;
  }
  __syncthreads();
  // geometric product: thread c computes gp[hh][c] for all 5 channels
  float gpv[5];
  #pragma unroll
  for (int hh=0; hh<5; hh++) {
    float a = 0.f;
    int n = GPT.cnt[c];
    for (int e=0; e<n; ++e) {
      a += GPT.ss[c][e]*sh1[tl][hh][GPT.ii[c][e]]*sh1[tl][5+hh][GPT.jj[c][e]];
    }
    gpv[hh] = a;
  }
  // gate by gelu(scalar component) -- lane c=0 of this token's 16-lane group
  int base = (tid & 63) & ~15;
  #pragma unroll
  for (int hh=0;hh<5;hh++) {
    float g0 = __shfl(gpv[hh], base);
    float u  = 0.7978845608028654f*(g0 + 0.044715f*g0*g0*g0);
    float gate = 0.5f*g0*(1.f + tanhf(u));
    gpv[hh] *= gate;
  }
  // final equi_linear (w2) + residual
  #pragma unroll
  for (int o=0;o<5;o++) {
    const float* w2r = w2 + g*25 + o*5;
    float a=0.f;
    #pragma unroll
    for (int i=0;i<5;i++) a += gpv[i]*w2r[i];
    ht[o*16+c] += a;
  }
}

// --------------------------------------------------------------------------
// K5: final equi_linear (w_out) + output extraction: 32 scalar components +
// 3 vector components (blades 5,6,8 of output channel 0).
// --------------------------------------------------------------------------
__global__ __launch_bounds__(256) void k_out(
    const float* __restrict__ h, const float* __restrict__ w_out,
    float* __restrict__ out)
{
  int gid = blockIdx.x*256 + threadIdx.x;
  if (gid >= NTOK*35) return;
  int j = gid % 35, token = gid / 35;
  const float* ht = h + (size_t)token*80;
  float a = 0.f;
  if (j < 32) {
    const float* w = w_out + j*5;              // grade 0, row j
    #pragma unroll
    for (int i=0;i<5;i++) a += ht[i*16 + 0]*w[i];
  } else {
    int c = (j==32)?5:((j==33)?6:8);
    const float* w = w_out + 2*160 + 0*5;      // grade 2, row 0
    #pragma unroll
    for (int i=0;i<5;i++) a += ht[i*16 + c]*w[i];
  }
  out[gid] = a;
}

// --------------------------------------------------------------------------
extern "C" void kernel_launch(void* const* d_in, const int* in_sizes, int n_in,
                              void* d_out, int out_size, void* d_ws, size_t ws_size,
                              hipStream_t stream) {
  const float* x     = (const float*)d_in[0];
  const float* w_in  = (const float*)d_in[1];
  const float* w_out = (const float*)d_in[2];
  const float* wq    = (const float*)d_in[3];
  const float* wk    = (const float*)d_in[4];
  const float* wv    = (const float*)d_in[5];
  const float* wo    = (const float*)d_in[6];
  const float* w1    = (const float*)d_in[7];
  const float* w2    = (const float*)d_in[8];
  float* out = (float*)d_out;

  float* h  = (float*)d_ws;            // 16384*80
  float* qf = h  + (size_t)NTOK*80;    // 16384*40
  float* kf = qf + (size_t)NTOK*40;    // 16384*40
  float* vf = kf + (size_t)NTOK*40;    // 16384*80

  k_init_h<<<(NTOK*5 + 255)/256, 256, 0, stream>>>(x, w_in, h);
  for (int blk=0; blk<3; ++blk) {
    k_ln_qkv<<<NTOK/16, 256, 0, stream>>>(h, wq+blk*125, wk+blk*125, wv+blk*125,
                                          qf, kf, vf);
    k_attn<<<dim3(NSEQ/32, NB), 256, 0, stream>>>(qf, kf, vf, wo+blk*125, h);
    k_mlp<<<NTOK/16, 256, 0, stream>>>(h, w1+blk*250, w2+blk*125);
  }
  k_out<<<(NTOK*35 + 255)/256, 256, 0, stream>>>(h, w_out, out);
}

// Round 3
// 870.085 us; speedup vs baseline: 3.6091x; 3.6091x over previous
//
#include <hip/hip_runtime.h>
#include <hip/hip_bf16.h>
#include <math.h>

typedef __attribute__((ext_vector_type(8)))  __bf16 bf16x8;
typedef __attribute__((ext_vector_type(16))) float  f32x16;

// ---------------------------------------------------------------------------
// GATr forward on MI355X. B=4, N=4096, H=5, BLK=3, INV=32, 16 blades.
// Metric (0,1,1,1) PGA. Blade order sorted by (grade, mask).
// Attention: MFMA bf16 with hi/lo split (fp32-grade numerics).
// ---------------------------------------------------------------------------

namespace ga {
constexpr int MASKS[16] = {0,1,2,4,8,3,5,6,9,10,12,7,11,13,14,15};
constexpr int popc4(int x){ return (x&1)+((x>>1)&1)+((x>>2)&1)+((x>>3)&1); }
constexpr int idx_of(int m){ int r=-1; for(int i=0;i<16;i++) if(MASKS[i]==m) r=i; return r; }
struct GPTab {
  int cnt[16];
  signed char ii[16][16];
  signed char jj[16][16];
  float ss[16][16];
};
constexpr GPTab make_gptab(){
  GPTab t{};
  for(int i=0;i<16;i++) for(int j=0;j<16;j++){
    int a=MASKS[i], b=MASKS[j];
    if((a&b&1)!=0) continue;           // e0^2 = 0 kills the term
    int sw=0;
    for(int bi=0;bi<4;bi++) if((b>>bi)&1) sw += popc4(a>>(bi+1));
    int k = idx_of(a^b);
    int c = t.cnt[k];
    t.ii[k][c]=(signed char)i; t.jj[k][c]=(signed char)j;
    t.ss[k][c]=(sw&1)? -1.0f : 1.0f;
    t.cnt[k]=c+1;
  }
  return t;
}
} // namespace ga

__device__ const ga::GPTab GPT = ga::make_gptab();
__constant__ int GRADE16[16] = {0,1,1,1,1,2,2,2,2,2,2,3,3,3,3,4};
// blades with INNER==1: idx {0,2,3,4,7,9,10,14} -> mask 0x469D; compressed pos:
__constant__ int CPOS16[16] = {0,-1,1,2,3,-1,-1,4,-1,5,6,-1,-1,-1,7,-1};

#define NTOK 16384   // B*N
#define NSEQ 4096
#define NB 4
#define QP 48        // q/k padded feature dim (40 real + 8 zero), bf16 hi/lo
#define VR 80        // v transposed feature rows

__device__ __forceinline__ unsigned bfbits(float x){
  unsigned u = __float_as_uint(x);
  return (u + 0x7FFFu + ((u>>16)&1u)) >> 16;      // RNE f32->bf16 (finite only)
}

// --------------------------------------------------------------------------
// K1: h[token][o][c] = equi_linear(mv, w_in); mv sparse: ch0 = {1, vec@5,6,8},
// ch1..31 scalar-only.
// --------------------------------------------------------------------------
__global__ __launch_bounds__(256) void k_init_h(
    const float* __restrict__ x, const float* __restrict__ w_in,
    float* __restrict__ h)
{
  int gid = blockIdx.x*256 + threadIdx.x;      // token*5 + o
  if (gid >= NTOK*5) return;
  int o = gid % 5, token = gid / 5;
  const float* xt = x + (size_t)token*35;
  const float* w0 = w_in + o*32;               // grade-0 block, row o
  float s = w0[0];                             // mv[0][0] = 1.0
  #pragma unroll
  for (int i=1;i<32;i++) s += w0[i]*xt[i];
  float w2c = w_in[2*160 + o*32 + 0];          // grade-2, input channel 0
  float* ht = h + (size_t)token*80 + o*16;
  #pragma unroll
  for (int c=0;c<16;c++) ht[c] = 0.f;
  ht[0] = s;
  ht[5] = w2c*xt[32];
  ht[6] = w2c*xt[33];
  ht[8] = w2c*xt[34];
}

// --------------------------------------------------------------------------
// K2: fused equi_layernorm + q,k,v equi_linear -> bf16 hi/lo staging.
// q/k: compressed 40 inner feats (q pre-scaled), padded to 48.
// v: transposed vT[b][feat(80)][n], hi/lo.
// --------------------------------------------------------------------------
__global__ __launch_bounds__(256) void k_ln_qkv(
    const float* __restrict__ h,
    const float* __restrict__ wq, const float* __restrict__ wk,
    const float* __restrict__ wv,
    __hip_bfloat16* __restrict__ qh, __hip_bfloat16* __restrict__ ql,
    __hip_bfloat16* __restrict__ kh, __hip_bfloat16* __restrict__ kl,
    __hip_bfloat16* __restrict__ vh, __hip_bfloat16* __restrict__ vl)
{
  int tid = threadIdx.x;
  int c   = tid & 15;
  int token = blockIdx.x*16 + (tid>>4);
  int b = token >> 12;          // /4096
  int n = token & 4095;
  const float* ht = h + (size_t)token*80;
  float hv[5];
  #pragma unroll
  for (int i=0;i<5;i++) hv[i] = ht[i*16 + c];
  bool inner = (0x469D >> c) & 1;
  float part = 0.f;
  if (inner) {
    #pragma unroll
    for (int i=0;i<5;i++) part += hv[i]*hv[i];
  }
  part += __shfl_xor(part, 1);
  part += __shfl_xor(part, 2);
  part += __shfl_xor(part, 4);
  part += __shfl_xor(part, 8);
  float denom = sqrtf(part*(1.f/80.f) + 1e-6f);
  float rinv = 1.f/denom;
  float rln[5];
  #pragma unroll
  for (int i=0;i<5;i++) rln[i] = hv[i]*rinv;

  int g = GRADE16[c];
  int cp = CPOS16[c];
  const float scale = 0.11180339887498949f;    // 1/sqrt(16*5)
  #pragma unroll
  for (int o=0;o<5;o++) {
    const float* wqr = wq + g*25 + o*5;
    const float* wkr = wk + g*25 + o*5;
    const float* wvr = wv + g*25 + o*5;
    float aq=0.f, ak=0.f, av=0.f;
    #pragma unroll
    for (int i=0;i<5;i++) {
      aq += rln[i]*wqr[i];
      ak += rln[i]*wkr[i];
      av += rln[i]*wvr[i];
    }
    __hip_bfloat16 vhi = __float2bfloat16(av);
    size_t vo = ((size_t)b*VR + o*16 + c)*NSEQ + n;
    vh[vo] = vhi;
    vl[vo] = __float2bfloat16(av - __bfloat162float(vhi));
    if (inner) {
      float aqs = aq*scale;
      __hip_bfloat16 qhi = __float2bfloat16(aqs);
      __hip_bfloat16 khi = __float2bfloat16(ak);
      size_t qo = (size_t)token*QP + o*8 + cp;
      qh[qo] = qhi;  ql[qo] = __float2bfloat16(aqs - __bfloat162float(qhi));
      kh[qo] = khi;  kl[qo] = __float2bfloat16(ak  - __bfloat162float(khi));
    }
  }
  // zero pads: feats 40..47
  if (c < 8) {
    size_t po = (size_t)token*QP + 40 + c;
    __hip_bfloat16 z = __float2bfloat16(0.f);
    qh[po]=z; ql[po]=z; kh[po]=z; kl[po]=z;
  }
}

// --------------------------------------------------------------------------
// K3: MFMA flash attention, hi/lo split, fused epilogue (normalize + wo
// projection + residual). One 64-thread block = one wave = 32 query rows.
// Swapped QK^T: S^T = mfma(A=K, B=Q^T) -> C col(lane&31)=q-row.
// --------------------------------------------------------------------------
__global__ __launch_bounds__(64, 1) void k_attn_mfma(
    const __hip_bfloat16* __restrict__ qh, const __hip_bfloat16* __restrict__ ql,
    const __hip_bfloat16* __restrict__ kh, const __hip_bfloat16* __restrict__ kl,
    const __hip_bfloat16* __restrict__ vh, const __hip_bfloat16* __restrict__ vl,
    const float* __restrict__ wo, float* __restrict__ h)
{
  __shared__ __align__(16) float satt[32][80];
  __shared__ __align__(16) float ldsb[32];
  __shared__ float sWo[125];
  int tid = threadIdx.x;
  int ln = tid & 31;
  int hf = tid >> 5;
  int b  = blockIdx.y;
  int rowbase = b*NSEQ + blockIdx.x*32;

  for (int i=tid; i<125; i+=64) sWo[i] = wo[i];

  // Q frags (B operand): B[k][j]: j=lane&31=qrow, k=(lane>>5)*8+e
  const __hip_bfloat16* qhp = qh + (size_t)(rowbase + ln)*QP + hf*8;
  const __hip_bfloat16* qlp = ql + (size_t)(rowbase + ln)*QP + hf*8;
  bf16x8 qh0 = *(const bf16x8*)(qhp);
  bf16x8 qh1 = *(const bf16x8*)(qhp + 16);
  bf16x8 qh2 = *(const bf16x8*)(qhp + 32);
  bf16x8 ql0 = *(const bf16x8*)(qlp);
  bf16x8 ql1 = *(const bf16x8*)(qlp + 16);
  bf16x8 ql2 = *(const bf16x8*)(qlp + 32);

  f32x16 acc0, acc1, acc2;
  #pragma unroll
  for (int r=0;r<16;r++){ acc0[r]=0.f; acc1[r]=0.f; acc2[r]=0.f; }
  float m = -1e30f, lsum = 0.f;

  int vrow2 = 64 + (ln & 15);                  // clamp: cols>=16 of block2 unused
  const __hip_bfloat16* vhb0 = vh + ((size_t)b*VR +      ln)*NSEQ + hf*8;
  const __hip_bfloat16* vhb1 = vh + ((size_t)b*VR + 32 + ln)*NSEQ + hf*8;
  const __hip_bfloat16* vhb2 = vh + ((size_t)b*VR +  vrow2)*NSEQ + hf*8;
  const __hip_bfloat16* vlb0 = vl + ((size_t)b*VR +      ln)*NSEQ + hf*8;
  const __hip_bfloat16* vlb1 = vl + ((size_t)b*VR + 32 + ln)*NSEQ + hf*8;
  const __hip_bfloat16* vlb2 = vl + ((size_t)b*VR +  vrow2)*NSEQ + hf*8;

  for (int koff=0; koff<NSEQ; koff+=32) {
    // K frags (A operand): A[i][k]: i=lane&31=key, k=(lane>>5)*8+e
    const __hip_bfloat16* khp = kh + (size_t)(b*NSEQ + koff + ln)*QP + hf*8;
    const __hip_bfloat16* klp = kl + (size_t)(b*NSEQ + koff + ln)*QP + hf*8;
    bf16x8 kh0 = *(const bf16x8*)(khp);
    bf16x8 kh1 = *(const bf16x8*)(khp + 16);
    bf16x8 kh2 = *(const bf16x8*)(khp + 32);
    bf16x8 kl0 = *(const bf16x8*)(klp);
    bf16x8 kl1 = *(const bf16x8*)(klp + 16);
    bf16x8 kl2 = *(const bf16x8*)(klp + 32);
    f32x16 S;
    #pragma unroll
    for (int r=0;r<16;r++) S[r]=0.f;
    S = __builtin_amdgcn_mfma_f32_32x32x16_bf16(kh0, qh0, S, 0,0,0);
    S = __builtin_amdgcn_mfma_f32_32x32x16_bf16(kh1, qh1, S, 0,0,0);
    S = __builtin_amdgcn_mfma_f32_32x32x16_bf16(kh2, qh2, S, 0,0,0);
    S = __builtin_amdgcn_mfma_f32_32x32x16_bf16(kh0, ql0, S, 0,0,0);
    S = __builtin_amdgcn_mfma_f32_32x32x16_bf16(kh1, ql1, S, 0,0,0);
    S = __builtin_amdgcn_mfma_f32_32x32x16_bf16(kh2, ql2, S, 0,0,0);
    S = __builtin_amdgcn_mfma_f32_32x32x16_bf16(kl0, qh0, S, 0,0,0);
    S = __builtin_amdgcn_mfma_f32_32x32x16_bf16(kl1, qh1, S, 0,0,0);
    S = __builtin_amdgcn_mfma_f32_32x32x16_bf16(kl2, qh2, S, 0,0,0);
    // S frag: lane holds q-row (ln); 16 keys: key(r) = (r&3)+8*(r>>2)+4*hf

    float tmax = S[0];
    #pragma unroll
    for (int r=1;r<16;r++) tmax = fmaxf(tmax, S[r]);
    tmax = fmaxf(tmax, __shfl_xor(tmax, 32));
    if (!__all(tmax <= m + 8.f)) {
      float mn = fmaxf(m, tmax);
      float f = __expf(m - mn);
      if (hf==0) ldsb[ln] = f;
      float fv[16];
      *(float4*)&fv[0]  = *(const float4*)&ldsb[ 0 + hf*4];
      *(float4*)&fv[4]  = *(const float4*)&ldsb[ 8 + hf*4];
      *(float4*)&fv[8]  = *(const float4*)&ldsb[16 + hf*4];
      *(float4*)&fv[12] = *(const float4*)&ldsb[24 + hf*4];
      #pragma unroll
      for (int r=0;r<16;r++){ float fr=fv[r]; acc0[r]*=fr; acc1[r]*=fr; acc2[r]*=fr; }
      lsum *= f;
      m = mn;
    }
    float p[16];
    #pragma unroll
    for (int r=0;r<16;r++) p[r] = __expf(S[r] - m);
    float ls = 0.f;
    #pragma unroll
    for (int r=0;r<16;r++) ls += p[r];
    ls += __shfl_xor(ls, 32);
    lsum += ls;

    // split P -> hi/lo packed pairs (key-order e: pairs (p[2e],p[2e+1]))
    unsigned hbp[8], lbp[8];
    #pragma unroll
    for (int e=0;e<8;e++) {
      unsigned h0 = bfbits(p[2*e]), h1 = bfbits(p[2*e+1]);
      float l0 = p[2*e]   - __uint_as_float(h0<<16);
      float l1 = p[2*e+1] - __uint_as_float(h1<<16);
      unsigned lo0 = bfbits(l0), lo1 = bfbits(l1);
      hbp[e] = h0  | (h1<<16);
      lbp[e] = lo0 | (lo1<<16);
    }
    // exchange halves: A0 covers keys 0..15, A1 keys 16..31
    union { unsigned u[4]; bf16x8 v; } A0h, A1h, A0l, A1l;
    {
      unsigned sa = hf ? hbp[0] : hbp[2], sb = hf ? hbp[1] : hbp[3];
      unsigned ra = __shfl_xor((int)sa,32), rb = __shfl_xor((int)sb,32);
      unsigned sc = hf ? hbp[4] : hbp[6], sd = hf ? hbp[5] : hbp[7];
      unsigned rc = __shfl_xor((int)sc,32), rd = __shfl_xor((int)sd,32);
      A0h.u[0] = hf ? ra     : hbp[0];  A0h.u[1] = hf ? rb     : hbp[1];
      A0h.u[2] = hf ? hbp[2] : ra;      A0h.u[3] = hf ? hbp[3] : rb;
      A1h.u[0] = hf ? rc     : hbp[4];  A1h.u[1] = hf ? rd     : hbp[5];
      A1h.u[2] = hf ? hbp[6] : rc;      A1h.u[3] = hf ? hbp[7] : rd;
    }
    {
      unsigned sa = hf ? lbp[0] : lbp[2], sb = hf ? lbp[1] : lbp[3];
      unsigned ra = __shfl_xor((int)sa,32), rb = __shfl_xor((int)sb,32);
      unsigned sc = hf ? lbp[4] : lbp[6], sd = hf ? lbp[5] : lbp[7];
      unsigned rc = __shfl_xor((int)sc,32), rd = __shfl_xor((int)sd,32);
      A0l.u[0] = hf ? ra     : lbp[0];  A0l.u[1] = hf ? rb     : lbp[1];
      A0l.u[2] = hf ? lbp[2] : ra;      A0l.u[3] = hf ? lbp[3] : rb;
      A1l.u[0] = hf ? rc     : lbp[4];  A1l.u[1] = hf ? rd     : lbp[5];
      A1l.u[2] = hf ? lbp[6] : rc;      A1l.u[3] = hf ? lbp[7] : rd;
    }

    // V frags: B[k][j]: j=lane&31=feat(in 32-block), k=(lane>>5)*8+e=key
    bf16x8 Bh00 = *(const bf16x8*)(vhb0 + koff);
    bf16x8 Bh01 = *(const bf16x8*)(vhb0 + koff + 16);
    bf16x8 Bh10 = *(const bf16x8*)(vhb1 + koff);
    bf16x8 Bh11 = *(const bf16x8*)(vhb1 + koff + 16);
    bf16x8 Bh20 = *(const bf16x8*)(vhb2 + koff);
    bf16x8 Bh21 = *(const bf16x8*)(vhb2 + koff + 16);
    bf16x8 Bl00 = *(const bf16x8*)(vlb0 + koff);
    bf16x8 Bl01 = *(const bf16x8*)(vlb0 + koff + 16);
    bf16x8 Bl10 = *(const bf16x8*)(vlb1 + koff);
    bf16x8 Bl11 = *(const bf16x8*)(vlb1 + koff + 16);
    bf16x8 Bl20 = *(const bf16x8*)(vlb2 + koff);
    bf16x8 Bl21 = *(const bf16x8*)(vlb2 + koff + 16);

    acc0 = __builtin_amdgcn_mfma_f32_32x32x16_bf16(A0h.v, Bh00, acc0, 0,0,0);
    acc0 = __builtin_amdgcn_mfma_f32_32x32x16_bf16(A1h.v, Bh01, acc0, 0,0,0);
    acc0 = __builtin_amdgcn_mfma_f32_32x32x16_bf16(A0h.v, Bl00, acc0, 0,0,0);
    acc0 = __builtin_amdgcn_mfma_f32_32x32x16_bf16(A1h.v, Bl01, acc0, 0,0,0);
    acc0 = __builtin_amdgcn_mfma_f32_32x32x16_bf16(A0l.v, Bh00, acc0, 0,0,0);
    acc0 = __builtin_amdgcn_mfma_f32_32x32x16_bf16(A1l.v, Bh01, acc0, 0,0,0);

    acc1 = __builtin_amdgcn_mfma_f32_32x32x16_bf16(A0h.v, Bh10, acc1, 0,0,0);
    acc1 = __builtin_amdgcn_mfma_f32_32x32x16_bf16(A1h.v, Bh11, acc1, 0,0,0);
    acc1 = __builtin_amdgcn_mfma_f32_32x32x16_bf16(A0h.v, Bl10, acc1, 0,0,0);
    acc1 = __builtin_amdgcn_mfma_f32_32x32x16_bf16(A1h.v, Bl11, acc1, 0,0,0);
    acc1 = __builtin_amdgcn_mfma_f32_32x32x16_bf16(A0l.v, Bh10, acc1, 0,0,0);
    acc1 = __builtin_amdgcn_mfma_f32_32x32x16_bf16(A1l.v, Bh11, acc1, 0,0,0);

    acc2 = __builtin_amdgcn_mfma_f32_32x32x16_bf16(A0h.v, Bh20, acc2, 0,0,0);
    acc2 = __builtin_amdgcn_mfma_f32_32x32x16_bf16(A1h.v, Bh21, acc2, 0,0,0);
    acc2 = __builtin_amdgcn_mfma_f32_32x32x16_bf16(A0h.v, Bl20, acc2, 0,0,0);
    acc2 = __builtin_amdgcn_mfma_f32_32x32x16_bf16(A1h.v, Bl21, acc2, 0,0,0);
    acc2 = __builtin_amdgcn_mfma_f32_32x32x16_bf16(A0l.v, Bh20, acc2, 0,0,0);
    acc2 = __builtin_amdgcn_mfma_f32_32x32x16_bf16(A1l.v, Bh21, acc2, 0,0,0);
  }

  // epilogue: normalize into LDS
  if (hf==0) ldsb[ln] = 1.f/lsum;
  float iv[16];
  *(float4*)&iv[0]  = *(const float4*)&ldsb[ 0 + hf*4];
  *(float4*)&iv[4]  = *(const float4*)&ldsb[ 8 + hf*4];
  *(float4*)&iv[8]  = *(const float4*)&ldsb[16 + hf*4];
  *(float4*)&iv[12] = *(const float4*)&ldsb[24 + hf*4];
  #pragma unroll
  for (int r=0;r<16;r++) {
    int row = (r&3) + 8*(r>>2) + 4*hf;
    satt[row][ln]      = acc0[r]*iv[r];
    satt[row][32+ln]   = acc1[r]*iv[r];
    if (ln < 16) satt[row][64+ln] = acc2[r]*iv[r];
  }
  __syncthreads();
  // wo-projection + residual: h[rowbase*80 + flat] += proj
  float* hb = h + (size_t)rowbase*80;
  #pragma unroll
  for (int e=0;e<40;e++) {
    int flat = e*64 + tid;
    int rr = flat/80, oc = flat - rr*80;
    int o = oc>>4, c = oc&15;
    int g = GRADE16[c];
    const float* wor = sWo + g*25 + o*5;
    float a = 0.f;
    #pragma unroll
    for (int i=0;i<5;i++) a += satt[rr][i*16+c]*wor[i];
    hb[flat] += a;
  }
}

// --------------------------------------------------------------------------
// K4: fused equi_layernorm + MLP (w1 -> geometric product -> gated gelu ->
// w2) + residual. 16 threads/token (one per output blade), 16 tokens/block.
// --------------------------------------------------------------------------
__global__ __launch_bounds__(256) void k_mlp(
    float* __restrict__ h,
    const float* __restrict__ w1, const float* __restrict__ w2)
{
  __shared__ float sh1[16][10][16];
  int tid = threadIdx.x;
  int c   = tid & 15;
  int tl  = tid >> 4;
  int token = blockIdx.x*16 + tl;
  float* ht = h + (size_t)token*80;
  float hv[5];
  #pragma unroll
  for (int i=0;i<5;i++) hv[i] = ht[i*16 + c];
  bool inner = (0x469D >> c) & 1;
  float part = 0.f;
  if (inner) {
    #pragma unroll
    for (int i=0;i<5;i++) part += hv[i]*hv[i];
  }
  part += __shfl_xor(part, 1);
  part += __shfl_xor(part, 2);
  part += __shfl_xor(part, 4);
  part += __shfl_xor(part, 8);
  float denom = sqrtf(part*(1.f/80.f) + 1e-6f);
  float rinv = 1.f/denom;
  float rln[5];
  #pragma unroll
  for (int i=0;i<5;i++) rln[i] = hv[i]*rinv;

  int g = GRADE16[c];
  #pragma unroll
  for (int o=0;o<10;o++) {
    const float* w1r = w1 + g*50 + o*5;
    float a=0.f;
    #pragma unroll
    for (int i=0;i<5;i++) a += rln[i]*w1r[i];
    sh1[tl][o][c] = a;
  }
  __syncthreads();
  // geometric product: thread c computes gp[hh][c] for all 5 channels
  float gpv[5];
  #pragma unroll
  for (int hh=0; hh<5; hh++) {
    float a = 0.f;
    int n = GPT.cnt[c];
    for (int e=0; e<n; ++e) {
      a += GPT.ss[c][e]*sh1[tl][hh][GPT.ii[c][e]]*sh1[tl][5+hh][GPT.jj[c][e]];
    }
    gpv[hh] = a;
  }
  // gate by gelu(scalar component) -- lane c=0 of this token's 16-lane group
  int base = (tid & 63) & ~15;
  #pragma unroll
  for (int hh=0;hh<5;hh++) {
    float g0 = __shfl(gpv[hh], base);
    float u  = 0.7978845608028654f*(g0 + 0.044715f*g0*g0*g0);
    float gate = 0.5f*g0*(1.f + tanhf(u));
    gpv[hh] *= gate;
  }
  // final equi_linear (w2) + residual
  #pragma unroll
  for (int o=0;o<5;o++) {
    const float* w2r = w2 + g*25 + o*5;
    float a=0.f;
    #pragma unroll
    for (int i=0;i<5;i++) a += gpv[i]*w2r[i];
    ht[o*16+c] += a;
  }
}

// --------------------------------------------------------------------------
// K5: final equi_linear (w_out) + output extraction: 32 scalar components +
// 3 vector components (blades 5,6,8 of output channel 0).
// --------------------------------------------------------------------------
__global__ __launch_bounds__(256) void k_out(
    const float* __restrict__ h, const float* __restrict__ w_out,
    float* __restrict__ out)
{
  int gid = blockIdx.x*256 + threadIdx.x;
  if (gid >= NTOK*35) return;
  int j = gid % 35, token = gid / 35;
  const float* ht = h + (size_t)token*80;
  float a = 0.f;
  if (j < 32) {
    const float* w = w_out + j*5;              // grade 0, row j
    #pragma unroll
    for (int i=0;i<5;i++) a += ht[i*16 + 0]*w[i];
  } else {
    int c = (j==32)?5:((j==33)?6:8);
    const float* w = w_out + 2*160 + 0*5;      // grade 2, row 0
    #pragma unroll
    for (int i=0;i<5;i++) a += ht[i*16 + c]*w[i];
  }
  out[gid] = a;
}

// --------------------------------------------------------------------------
extern "C" void kernel_launch(void* const* d_in, const int* in_sizes, int n_in,
                              void* d_out, int out_size, void* d_ws, size_t ws_size,
                              hipStream_t stream) {
  const float* x     = (const float*)d_in[0];
  const float* w_in  = (const float*)d_in[1];
  const float* w_out = (const float*)d_in[2];
  const float* wq    = (const float*)d_in[3];
  const float* wk    = (const float*)d_in[4];
  const float* wv    = (const float*)d_in[5];
  const float* wo    = (const float*)d_in[6];
  const float* w1    = (const float*)d_in[7];
  const float* w2    = (const float*)d_in[8];
  float* out = (float*)d_out;

  // workspace carve: h(fp32) + ql,kh,kl(48 bf16/token) + vh,vl(80 rows bf16)
  // = 15,204,352 B. q_hi lives in d_out (2.29MB, dead until k_out).
  char* p = (char*)d_ws;
  float* h = (float*)p;                      p += (size_t)NTOK*80*4;
  __hip_bfloat16* ql = (__hip_bfloat16*)p;   p += (size_t)NTOK*QP*2;
  __hip_bfloat16* kh = (__hip_bfloat16*)p;   p += (size_t)NTOK*QP*2;
  __hip_bfloat16* kl = (__hip_bfloat16*)p;   p += (size_t)NTOK*QP*2;
  __hip_bfloat16* vh = (__hip_bfloat16*)p;   p += (size_t)NB*VR*NSEQ*2;
  __hip_bfloat16* vl = (__hip_bfloat16*)p;
  __hip_bfloat16* qh = (__hip_bfloat16*)d_out;   // 1.57MB <= 2.29MB

  k_init_h<<<(NTOK*5 + 255)/256, 256, 0, stream>>>(x, w_in, h);
  for (int blk=0; blk<3; ++blk) {
    k_ln_qkv<<<NTOK/16, 256, 0, stream>>>(h, wq+blk*125, wk+blk*125, wv+blk*125,
                                          qh, ql, kh, kl, vh, vl);
    k_attn_mfma<<<dim3(NSEQ/32, NB), 64, 0, stream>>>(qh, ql, kh, kl, vh, vl,
                                                      wo+blk*125, h);
    k_mlp<<<NTOK/16, 256, 0, stream>>>(h, w1+blk*250, w2+blk*125);
  }
  k_out<<<(NTOK*35 + 255)/256, 256, 0, stream>>>(h, w_out, out);
}

// Round 4
// 653.498 us; speedup vs baseline: 4.8053x; 1.3314x over previous
//
#include <hip/hip_runtime.h>
#include <hip/hip_bf16.h>
#include <math.h>

typedef __attribute__((ext_vector_type(8)))  __bf16 bf16x8;
typedef __attribute__((ext_vector_type(16))) float  f32x16;

// ---------------------------------------------------------------------------
// GATr forward on MI355X. B=4, N=4096, H=5, BLK=3, INV=32, 16 blades.
// Metric (0,1,1,1) PGA. Blade order sorted by (grade, mask).
// Attention: MFMA bf16 hi/lo split (fp32-grade), 8-way intra-block key-split.
// ---------------------------------------------------------------------------

namespace ga {
constexpr int MASKS[16] = {0,1,2,4,8,3,5,6,9,10,12,7,11,13,14,15};
constexpr int popc4(int x){ return (x&1)+((x>>1)&1)+((x>>2)&1)+((x>>3)&1); }
constexpr int idx_of(int m){ int r=-1; for(int i=0;i<16;i++) if(MASKS[i]==m) r=i; return r; }
struct GPTab {
  int cnt[16];
  signed char ii[16][16];
  signed char jj[16][16];
  float ss[16][16];
};
constexpr GPTab make_gptab(){
  GPTab t{};
  for(int i=0;i<16;i++) for(int j=0;j<16;j++){
    int a=MASKS[i], b=MASKS[j];
    if((a&b&1)!=0) continue;           // e0^2 = 0 kills the term
    int sw=0;
    for(int bi=0;bi<4;bi++) if((b>>bi)&1) sw += popc4(a>>(bi+1));
    int k = idx_of(a^b);
    int c = t.cnt[k];
    t.ii[k][c]=(signed char)i; t.jj[k][c]=(signed char)j;
    t.ss[k][c]=(sw&1)? -1.0f : 1.0f;
    t.cnt[k]=c+1;
  }
  return t;
}
} // namespace ga

__device__ const ga::GPTab GPT = ga::make_gptab();
__constant__ int GRADE16[16] = {0,1,1,1,1,2,2,2,2,2,2,3,3,3,3,4};
// blades with INNER==1: idx {0,2,3,4,7,9,10,14} -> mask 0x469D; compressed pos:
__constant__ int CPOS16[16] = {0,-1,1,2,3,-1,-1,4,-1,5,6,-1,-1,-1,7,-1};

#define NTOK 16384   // B*N
#define NSEQ 4096
#define NB 4
#define QP 48        // q/k padded feature dim (40 real + 8 zero), bf16 hi/lo
#define VR 80        // v transposed feature rows
#define NW 8         // waves per attention block (key-split factor)

__device__ __forceinline__ unsigned bfbits(float x){
  unsigned u = __float_as_uint(x);
  return (u + 0x7FFFu + ((u>>16)&1u)) >> 16;      // RNE f32->bf16 (finite only)
}

// --------------------------------------------------------------------------
// K1: h[token][o][c] = equi_linear(mv, w_in); mv sparse.
// --------------------------------------------------------------------------
__global__ __launch_bounds__(256) void k_init_h(
    const float* __restrict__ x, const float* __restrict__ w_in,
    float* __restrict__ h)
{
  int gid = blockIdx.x*256 + threadIdx.x;      // token*5 + o
  if (gid >= NTOK*5) return;
  int o = gid % 5, token = gid / 5;
  const float* xt = x + (size_t)token*35;
  const float* w0 = w_in + o*32;               // grade-0 block, row o
  float s = w0[0];                             // mv[0][0] = 1.0
  #pragma unroll
  for (int i=1;i<32;i++) s += w0[i]*xt[i];
  float w2c = w_in[2*160 + o*32 + 0];          // grade-2, input channel 0
  float* ht = h + (size_t)token*80 + o*16;
  #pragma unroll
  for (int c=0;c<16;c++) ht[c] = 0.f;
  ht[0] = s;
  ht[5] = w2c*xt[32];
  ht[6] = w2c*xt[33];
  ht[8] = w2c*xt[34];
}

// --------------------------------------------------------------------------
// K2: fused equi_layernorm + q,k,v equi_linear -> bf16 hi/lo staging.
// --------------------------------------------------------------------------
__global__ __launch_bounds__(256) void k_ln_qkv(
    const float* __restrict__ h,
    const float* __restrict__ wq, const float* __restrict__ wk,
    const float* __restrict__ wv,
    __hip_bfloat16* __restrict__ qh, __hip_bfloat16* __restrict__ ql,
    __hip_bfloat16* __restrict__ kh, __hip_bfloat16* __restrict__ kl,
    __hip_bfloat16* __restrict__ vh, __hip_bfloat16* __restrict__ vl)
{
  int tid = threadIdx.x;
  int c   = tid & 15;
  int token = blockIdx.x*16 + (tid>>4);
  int b = token >> 12;          // /4096
  int n = token & 4095;
  const float* ht = h + (size_t)token*80;
  float hv[5];
  #pragma unroll
  for (int i=0;i<5;i++) hv[i] = ht[i*16 + c];
  bool inner = (0x469D >> c) & 1;
  float part = 0.f;
  if (inner) {
    #pragma unroll
    for (int i=0;i<5;i++) part += hv[i]*hv[i];
  }
  part += __shfl_xor(part, 1);
  part += __shfl_xor(part, 2);
  part += __shfl_xor(part, 4);
  part += __shfl_xor(part, 8);
  float denom = sqrtf(part*(1.f/80.f) + 1e-6f);
  float rinv = 1.f/denom;
  float rln[5];
  #pragma unroll
  for (int i=0;i<5;i++) rln[i] = hv[i]*rinv;

  int g = GRADE16[c];
  int cp = CPOS16[c];
  const float scale = 0.11180339887498949f;    // 1/sqrt(16*5)
  #pragma unroll
  for (int o=0;o<5;o++) {
    const float* wqr = wq + g*25 + o*5;
    const float* wkr = wk + g*25 + o*5;
    const float* wvr = wv + g*25 + o*5;
    float aq=0.f, ak=0.f, av=0.f;
    #pragma unroll
    for (int i=0;i<5;i++) {
      aq += rln[i]*wqr[i];
      ak += rln[i]*wkr[i];
      av += rln[i]*wvr[i];
    }
    __hip_bfloat16 vhi = __float2bfloat16(av);
    size_t vo = ((size_t)b*VR + o*16 + c)*NSEQ + n;
    vh[vo] = vhi;
    vl[vo] = __float2bfloat16(av - __bfloat162float(vhi));
    if (inner) {
      float aqs = aq*scale;
      __hip_bfloat16 qhi = __float2bfloat16(aqs);
      __hip_bfloat16 khi = __float2bfloat16(ak);
      size_t qo = (size_t)token*QP + o*8 + cp;
      qh[qo] = qhi;  ql[qo] = __float2bfloat16(aqs - __bfloat162float(qhi));
      kh[qo] = khi;  kl[qo] = __float2bfloat16(ak  - __bfloat162float(khi));
    }
  }
  // zero pads: feats 40..47
  if (c < 8) {
    size_t po = (size_t)token*QP + 40 + c;
    __hip_bfloat16 z = __float2bfloat16(0.f);
    qh[po]=z; ql[po]=z; kh[po]=z; kl[po]=z;
  }
}

// --------------------------------------------------------------------------
// K3: MFMA flash attention, hi/lo split, 8-way intra-block key-split with
// LDS merge, fused epilogue (normalize + wo projection + residual).
// Block = 512 thr = 8 waves, one 32-row Q-tile; wave w covers keys
// [w*512, w*512+512). Swapped QK^T: S = mfma(A=K, B=Q) -> C col = q-row.
// --------------------------------------------------------------------------
__global__ __launch_bounds__(512, 4) void k_attn_mfma(
    const __hip_bfloat16* __restrict__ qh, const __hip_bfloat16* __restrict__ ql,
    const __hip_bfloat16* __restrict__ kh, const __hip_bfloat16* __restrict__ kl,
    const __hip_bfloat16* __restrict__ vh, const __hip_bfloat16* __restrict__ vl,
    const float* __restrict__ wo, float* __restrict__ h)
{
  __shared__ __align__(16) float satt[32][80];
  __shared__ __align__(16) float ldsb[NW][32];
  __shared__ __align__(16) float sM[NW][32];
  __shared__ __align__(16) float sL[NW][32];
  __shared__ __align__(16) float sMax[32];
  __shared__ __align__(16) float sInv[32];
  __shared__ float sWo[125];
  int tid = threadIdx.x;
  int w  = tid >> 6;
  int ln = tid & 31;
  int hf = (tid >> 5) & 1;
  int b  = blockIdx.y;
  int rowbase = b*NSEQ + blockIdx.x*32;

  for (int i=tid; i<125; i+=512) sWo[i] = wo[i];
  for (int i=tid; i<2560; i+=512) ((float*)satt)[i] = 0.f;

  // Q frags (B operand): B[k][j]: j=lane&31=qrow, k=(lane>>5)*8+e
  const __hip_bfloat16* qhp = qh + (size_t)(rowbase + ln)*QP + hf*8;
  const __hip_bfloat16* qlp = ql + (size_t)(rowbase + ln)*QP + hf*8;
  bf16x8 qh0 = *(const bf16x8*)(qhp);
  bf16x8 qh1 = *(const bf16x8*)(qhp + 16);
  bf16x8 qh2 = *(const bf16x8*)(qhp + 32);
  bf16x8 ql0 = *(const bf16x8*)(qlp);
  bf16x8 ql1 = *(const bf16x8*)(qlp + 16);
  bf16x8 ql2 = *(const bf16x8*)(qlp + 32);

  f32x16 acc0, acc1, acc2;
  #pragma unroll
  for (int r=0;r<16;r++){ acc0[r]=0.f; acc1[r]=0.f; acc2[r]=0.f; }
  float m = -1e30f, lsum = 0.f;

  int vrow2 = 64 + (ln & 15);                  // clamp: cols>=16 of block2 unused
  const __hip_bfloat16* vhb0 = vh + ((size_t)b*VR +      ln)*NSEQ + hf*8;
  const __hip_bfloat16* vhb1 = vh + ((size_t)b*VR + 32 + ln)*NSEQ + hf*8;
  const __hip_bfloat16* vhb2 = vh + ((size_t)b*VR +  vrow2)*NSEQ + hf*8;
  const __hip_bfloat16* vlb0 = vl + ((size_t)b*VR +      ln)*NSEQ + hf*8;
  const __hip_bfloat16* vlb1 = vl + ((size_t)b*VR + 32 + ln)*NSEQ + hf*8;
  const __hip_bfloat16* vlb2 = vl + ((size_t)b*VR +  vrow2)*NSEQ + hf*8;

  int kbeg = w*(NSEQ/NW), kend = kbeg + NSEQ/NW;
  for (int koff=kbeg; koff<kend; koff+=32) {
    // K frags (A operand): A[i][k]: i=lane&31=key, k=(lane>>5)*8+e
    const __hip_bfloat16* khp = kh + (size_t)(b*NSEQ + koff + ln)*QP + hf*8;
    const __hip_bfloat16* klp = kl + (size_t)(b*NSEQ + koff + ln)*QP + hf*8;
    bf16x8 kh0 = *(const bf16x8*)(khp);
    bf16x8 kh1 = *(const bf16x8*)(khp + 16);
    bf16x8 kh2 = *(const bf16x8*)(khp + 32);
    bf16x8 kl0 = *(const bf16x8*)(klp);
    bf16x8 kl1 = *(const bf16x8*)(klp + 16);
    bf16x8 kl2 = *(const bf16x8*)(klp + 32);
    f32x16 S;
    #pragma unroll
    for (int r=0;r<16;r++) S[r]=0.f;
    S = __builtin_amdgcn_mfma_f32_32x32x16_bf16(kh0, qh0, S, 0,0,0);
    S = __builtin_amdgcn_mfma_f32_32x32x16_bf16(kh1, qh1, S, 0,0,0);
    S = __builtin_amdgcn_mfma_f32_32x32x16_bf16(kh2, qh2, S, 0,0,0);
    S = __builtin_amdgcn_mfma_f32_32x32x16_bf16(kh0, ql0, S, 0,0,0);
    S = __builtin_amdgcn_mfma_f32_32x32x16_bf16(kh1, ql1, S, 0,0,0);
    S = __builtin_amdgcn_mfma_f32_32x32x16_bf16(kh2, ql2, S, 0,0,0);
    S = __builtin_amdgcn_mfma_f32_32x32x16_bf16(kl0, qh0, S, 0,0,0);
    S = __builtin_amdgcn_mfma_f32_32x32x16_bf16(kl1, qh1, S, 0,0,0);
    S = __builtin_amdgcn_mfma_f32_32x32x16_bf16(kl2, qh2, S, 0,0,0);
    // S frag: lane holds q-row (ln); 16 keys: key(r) = (r&3)+8*(r>>2)+4*hf

    float tmax = S[0];
    #pragma unroll
    for (int r=1;r<16;r++) tmax = fmaxf(tmax, S[r]);
    tmax = fmaxf(tmax, __shfl_xor(tmax, 32));
    if (!__all(tmax <= m + 8.f)) {
      float mn = fmaxf(m, tmax);
      float f = __expf(m - mn);
      if (hf==0) ldsb[w][ln] = f;
      float fv[16];
      *(float4*)&fv[0]  = *(const float4*)&ldsb[w][ 0 + hf*4];
      *(float4*)&fv[4]  = *(const float4*)&ldsb[w][ 8 + hf*4];
      *(float4*)&fv[8]  = *(const float4*)&ldsb[w][16 + hf*4];
      *(float4*)&fv[12] = *(const float4*)&ldsb[w][24 + hf*4];
      #pragma unroll
      for (int r=0;r<16;r++){ float fr=fv[r]; acc0[r]*=fr; acc1[r]*=fr; acc2[r]*=fr; }
      lsum *= f;
      m = mn;
    }
    float p[16];
    #pragma unroll
    for (int r=0;r<16;r++) p[r] = __expf(S[r] - m);
    float ls = 0.f;
    #pragma unroll
    for (int r=0;r<16;r++) ls += p[r];
    ls += __shfl_xor(ls, 32);
    lsum += ls;

    // split P -> hi/lo packed pairs (key-order e: pairs (p[2e],p[2e+1]))
    unsigned hbp[8], lbp[8];
    #pragma unroll
    for (int e=0;e<8;e++) {
      unsigned h0 = bfbits(p[2*e]), h1 = bfbits(p[2*e+1]);
      float l0 = p[2*e]   - __uint_as_float(h0<<16);
      float l1 = p[2*e+1] - __uint_as_float(h1<<16);
      unsigned lo0 = bfbits(l0), lo1 = bfbits(l1);
      hbp[e] = h0  | (h1<<16);
      lbp[e] = lo0 | (lo1<<16);
    }
    // exchange halves: A0 covers keys 0..15, A1 keys 16..31
    union { unsigned u[4]; bf16x8 v; } A0h, A1h, A0l, A1l;
    {
      unsigned sa = hf ? hbp[0] : hbp[2], sb = hf ? hbp[1] : hbp[3];
      unsigned ra = __shfl_xor((int)sa,32), rb = __shfl_xor((int)sb,32);
      unsigned sc = hf ? hbp[4] : hbp[6], sd = hf ? hbp[5] : hbp[7];
      unsigned rc = __shfl_xor((int)sc,32), rd = __shfl_xor((int)sd,32);
      A0h.u[0] = hf ? ra     : hbp[0];  A0h.u[1] = hf ? rb     : hbp[1];
      A0h.u[2] = hf ? hbp[2] : ra;      A0h.u[3] = hf ? hbp[3] : rb;
      A1h.u[0] = hf ? rc     : hbp[4];  A1h.u[1] = hf ? rd     : hbp[5];
      A1h.u[2] = hf ? hbp[6] : rc;      A1h.u[3] = hf ? hbp[7] : rd;
    }
    {
      unsigned sa = hf ? lbp[0] : lbp[2], sb = hf ? lbp[1] : lbp[3];
      unsigned ra = __shfl_xor((int)sa,32), rb = __shfl_xor((int)sb,32);
      unsigned sc = hf ? lbp[4] : lbp[6], sd = hf ? lbp[5] : lbp[7];
      unsigned rc = __shfl_xor((int)sc,32), rd = __shfl_xor((int)sd,32);
      A0l.u[0] = hf ? ra     : lbp[0];  A0l.u[1] = hf ? rb     : lbp[1];
      A0l.u[2] = hf ? lbp[2] : ra;      A0l.u[3] = hf ? lbp[3] : rb;
      A1l.u[0] = hf ? rc     : lbp[4];  A1l.u[1] = hf ? rd     : lbp[5];
      A1l.u[2] = hf ? lbp[6] : rc;      A1l.u[3] = hf ? lbp[7] : rd;
    }

    // V frags: B[k][j]: j=lane&31=feat(in 32-block), k=(lane>>5)*8+e=key
    bf16x8 Bh00 = *(const bf16x8*)(vhb0 + koff);
    bf16x8 Bh01 = *(const bf16x8*)(vhb0 + koff + 16);
    bf16x8 Bh10 = *(const bf16x8*)(vhb1 + koff);
    bf16x8 Bh11 = *(const bf16x8*)(vhb1 + koff + 16);
    bf16x8 Bh20 = *(const bf16x8*)(vhb2 + koff);
    bf16x8 Bh21 = *(const bf16x8*)(vhb2 + koff + 16);
    bf16x8 Bl00 = *(const bf16x8*)(vlb0 + koff);
    bf16x8 Bl01 = *(const bf16x8*)(vlb0 + koff + 16);
    bf16x8 Bl10 = *(const bf16x8*)(vlb1 + koff);
    bf16x8 Bl11 = *(const bf16x8*)(vlb1 + koff + 16);
    bf16x8 Bl20 = *(const bf16x8*)(vlb2 + koff);
    bf16x8 Bl21 = *(const bf16x8*)(vlb2 + koff + 16);

    acc0 = __builtin_amdgcn_mfma_f32_32x32x16_bf16(A0h.v, Bh00, acc0, 0,0,0);
    acc0 = __builtin_amdgcn_mfma_f32_32x32x16_bf16(A1h.v, Bh01, acc0, 0,0,0);
    acc0 = __builtin_amdgcn_mfma_f32_32x32x16_bf16(A0h.v, Bl00, acc0, 0,0,0);
    acc0 = __builtin_amdgcn_mfma_f32_32x32x16_bf16(A1h.v, Bl01, acc0, 0,0,0);
    acc0 = __builtin_amdgcn_mfma_f32_32x32x16_bf16(A0l.v, Bh00, acc0, 0,0,0);
    acc0 = __builtin_amdgcn_mfma_f32_32x32x16_bf16(A1l.v, Bh01, acc0, 0,0,0);

    acc1 = __builtin_amdgcn_mfma_f32_32x32x16_bf16(A0h.v, Bh10, acc1, 0,0,0);
    acc1 = __builtin_amdgcn_mfma_f32_32x32x16_bf16(A1h.v, Bh11, acc1, 0,0,0);
    acc1 = __builtin_amdgcn_mfma_f32_32x32x16_bf16(A0h.v, Bl10, acc1, 0,0,0);
    acc1 = __builtin_amdgcn_mfma_f32_32x32x16_bf16(A1h.v, Bl11, acc1, 0,0,0);
    acc1 = __builtin_amdgcn_mfma_f32_32x32x16_bf16(A0l.v, Bh10, acc1, 0,0,0);
    acc1 = __builtin_amdgcn_mfma_f32_32x32x16_bf16(A1l.v, Bh11, acc1, 0,0,0);

    acc2 = __builtin_amdgcn_mfma_f32_32x32x16_bf16(A0h.v, Bh20, acc2, 0,0,0);
    acc2 = __builtin_amdgcn_mfma_f32_32x32x16_bf16(A1h.v, Bh21, acc2, 0,0,0);
    acc2 = __builtin_amdgcn_mfma_f32_32x32x16_bf16(A0h.v, Bl20, acc2, 0,0,0);
    acc2 = __builtin_amdgcn_mfma_f32_32x32x16_bf16(A1h.v, Bl21, acc2, 0,0,0);
    acc2 = __builtin_amdgcn_mfma_f32_32x32x16_bf16(A0l.v, Bh20, acc2, 0,0,0);
    acc2 = __builtin_amdgcn_mfma_f32_32x32x16_bf16(A1l.v, Bh21, acc2, 0,0,0);
  }

  // ---- cross-wave merge ----
  if (hf==0) { sM[w][ln] = m; sL[w][ln] = lsum; }
  __syncthreads();
  if (tid < 32) {
    float M = sM[0][tid];
    #pragma unroll
    for (int u=1;u<NW;u++) M = fmaxf(M, sM[u][tid]);
    float L = 0.f;
    #pragma unroll
    for (int u=0;u<NW;u++) L += __expf(sM[u][tid] - M)*sL[u][tid];
    sMax[tid] = M;
    sInv[tid] = 1.f/L;
  }
  __syncthreads();
  // per-wave scale factor in C-frag row layout, accumulate into satt
  {
    float sm[16], sx[16];
    *(float4*)&sm[0]  = *(const float4*)&sM[w][ 0 + hf*4];
    *(float4*)&sm[4]  = *(const float4*)&sM[w][ 8 + hf*4];
    *(float4*)&sm[8]  = *(const float4*)&sM[w][16 + hf*4];
    *(float4*)&sm[12] = *(const float4*)&sM[w][24 + hf*4];
    *(float4*)&sx[0]  = *(const float4*)&sMax[ 0 + hf*4];
    *(float4*)&sx[4]  = *(const float4*)&sMax[ 8 + hf*4];
    *(float4*)&sx[8]  = *(const float4*)&sMax[16 + hf*4];
    *(float4*)&sx[12] = *(const float4*)&sMax[24 + hf*4];
    #pragma unroll
    for (int r=0;r<16;r++) {
      int row = (r&3) + 8*(r>>2) + 4*hf;
      float f = __expf(sm[r] - sx[r]);
      atomicAdd(&satt[row][ln],    f*acc0[r]);
      atomicAdd(&satt[row][32+ln], f*acc1[r]);
      if (ln < 16) atomicAdd(&satt[row][64+ln], f*acc2[r]);
    }
  }
  __syncthreads();
  // wo-projection + residual: h[rowbase*80 + flat] += proj
  float* hb = h + (size_t)rowbase*80;
  #pragma unroll
  for (int e=0;e<5;e++) {
    int flat = e*512 + tid;
    int rr = flat/80, oc = flat - rr*80;
    int o = oc>>4, c = oc&15;
    int g = GRADE16[c];
    const float* wor = sWo + g*25 + o*5;
    float a = 0.f;
    #pragma unroll
    for (int i=0;i<5;i++) a += satt[rr][i*16+c]*wor[i];
    hb[flat] += a*sInv[rr];
  }
}

// --------------------------------------------------------------------------
// K4: fused equi_layernorm + MLP (w1 -> geometric product -> gated gelu ->
// w2) + residual. 16 threads/token (one per output blade), 16 tokens/block.
// --------------------------------------------------------------------------
__global__ __launch_bounds__(256) void k_mlp(
    float* __restrict__ h,
    const float* __restrict__ w1, const float* __restrict__ w2)
{
  __shared__ float sh1[16][10][16];
  int tid = threadIdx.x;
  int c   = tid & 15;
  int tl  = tid >> 4;
  int token = blockIdx.x*16 + tl;
  float* ht = h + (size_t)token*80;
  float hv[5];
  #pragma unroll
  for (int i=0;i<5;i++) hv[i] = ht[i*16 + c];
  bool inner = (0x469D >> c) & 1;
  float part = 0.f;
  if (inner) {
    #pragma unroll
    for (int i=0;i<5;i++) part += hv[i]*hv[i];
  }
  part += __shfl_xor(part, 1);
  part += __shfl_xor(part, 2);
  part += __shfl_xor(part, 4);
  part += __shfl_xor(part, 8);
  float denom = sqrtf(part*(1.f/80.f) + 1e-6f);
  float rinv = 1.f/denom;
  float rln[5];
  #pragma unroll
  for (int i=0;i<5;i++) rln[i] = hv[i]*rinv;

  int g = GRADE16[c];
  #pragma unroll
  for (int o=0;o<10;o++) {
    const float* w1r = w1 + g*50 + o*5;
    float a=0.f;
    #pragma unroll
    for (int i=0;i<5;i++) a += rln[i]*w1r[i];
    sh1[tl][o][c] = a;
  }
  __syncthreads();
  // geometric product: thread c computes gp[hh][c] for all 5 channels
  float gpv[5];
  #pragma unroll
  for (int hh=0; hh<5; hh++) {
    float a = 0.f;
    int n = GPT.cnt[c];
    for (int e=0; e<n; ++e) {
      a += GPT.ss[c][e]*sh1[tl][hh][GPT.ii[c][e]]*sh1[tl][5+hh][GPT.jj[c][e]];
    }
    gpv[hh] = a;
  }
  // gate by gelu(scalar component) -- lane c=0 of this token's 16-lane group
  int base = (tid & 63) & ~15;
  #pragma unroll
  for (int hh=0;hh<5;hh++) {
    float g0 = __shfl(gpv[hh], base);
    float u  = 0.7978845608028654f*(g0 + 0.044715f*g0*g0*g0);
    float gate = 0.5f*g0*(1.f + tanhf(u));
    gpv[hh] *= gate;
  }
  // final equi_linear (w2) + residual
  #pragma unroll
  for (int o=0;o<5;o++) {
    const float* w2r = w2 + g*25 + o*5;
    float a=0.f;
    #pragma unroll
    for (int i=0;i<5;i++) a += gpv[i]*w2r[i];
    ht[o*16+c] += a;
  }
}

// --------------------------------------------------------------------------
// K5: final equi_linear (w_out) + output extraction.
// --------------------------------------------------------------------------
__global__ __launch_bounds__(256) void k_out(
    const float* __restrict__ h, const float* __restrict__ w_out,
    float* __restrict__ out)
{
  int gid = blockIdx.x*256 + threadIdx.x;
  if (gid >= NTOK*35) return;
  int j = gid % 35, token = gid / 35;
  const float* ht = h + (size_t)token*80;
  float a = 0.f;
  if (j < 32) {
    const float* w = w_out + j*5;              // grade 0, row j
    #pragma unroll
    for (int i=0;i<5;i++) a += ht[i*16 + 0]*w[i];
  } else {
    int c = (j==32)?5:((j==33)?6:8);
    const float* w = w_out + 2*160 + 0*5;      // grade 2, row 0
    #pragma unroll
    for (int i=0;i<5;i++) a += ht[i*16 + c]*w[i];
  }
  out[gid] = a;
}

// --------------------------------------------------------------------------
extern "C" void kernel_launch(void* const* d_in, const int* in_sizes, int n_in,
                              void* d_out, int out_size, void* d_ws, size_t ws_size,
                              hipStream_t stream) {
  const float* x     = (const float*)d_in[0];
  const float* w_in  = (const float*)d_in[1];
  const float* w_out = (const float*)d_in[2];
  const float* wq    = (const float*)d_in[3];
  const float* wk    = (const float*)d_in[4];
  const float* wv    = (const float*)d_in[5];
  const float* wo    = (const float*)d_in[6];
  const float* w1    = (const float*)d_in[7];
  const float* w2    = (const float*)d_in[8];
  float* out = (float*)d_out;

  // workspace carve: h(fp32) + ql,kh,kl(48 bf16/token) + vh,vl(80 rows bf16)
  // = 15,204,352 B. q_hi lives in d_out (1.57MB <= 2.29MB, dead until k_out).
  char* p = (char*)d_ws;
  float* h = (float*)p;                      p += (size_t)NTOK*80*4;
  __hip_bfloat16* ql = (__hip_bfloat16*)p;   p += (size_t)NTOK*QP*2;
  __hip_bfloat16* kh = (__hip_bfloat16*)p;   p += (size_t)NTOK*QP*2;
  __hip_bfloat16* kl = (__hip_bfloat16*)p;   p += (size_t)NTOK*QP*2;
  __hip_bfloat16* vh = (__hip_bfloat16*)p;   p += (size_t)NB*VR*NSEQ*2;
  __hip_bfloat16* vl = (__hip_bfloat16*)p;
  __hip_bfloat16* qh = (__hip_bfloat16*)d_out;

  k_init_h<<<(NTOK*5 + 255)/256, 256, 0, stream>>>(x, w_in, h);
  for (int blk=0; blk<3; ++blk) {
    k_ln_qkv<<<NTOK/16, 256, 0, stream>>>(h, wq+blk*125, wk+blk*125, wv+blk*125,
                                          qh, ql, kh, kl, vh, vl);
    k_attn_mfma<<<dim3(NSEQ/32, NB), 512, 0, stream>>>(qh, ql, kh, kl, vh, vl,
                                                       wo+blk*125, h);
    k_mlp<<<NTOK/16, 256, 0, stream>>>(h, w1+blk*250, w2+blk*125);
  }
  k_out<<<(NTOK*35 + 255)/256, 256, 0, stream>>>(h, w_out, out);
}

// Round 5
// 544.651 us; speedup vs baseline: 5.7656x; 1.1998x over previous
//
#include <hip/hip_runtime.h>
#include <hip/hip_bf16.h>
#include <math.h>

typedef __attribute__((ext_vector_type(8)))  __bf16 bf16x8;
typedef __attribute__((ext_vector_type(16))) float  f32x16;

// ---------------------------------------------------------------------------
// GATr forward on MI355X. B=4, N=4096, H=5, BLK=3, INV=32, 16 blades.
// Metric (0,1,1,1) PGA. Blade order sorted by (grade, mask).
// Attention: MFMA bf16 hi/lo split (fp32-grade), 8-way intra-block key-split,
// tile-major V layout for coalesced PV fragment loads.
// ---------------------------------------------------------------------------

namespace ga {
constexpr int MASKS[16] = {0,1,2,4,8,3,5,6,9,10,12,7,11,13,14,15};
constexpr int popc4(int x){ return (x&1)+((x>>1)&1)+((x>>2)&1)+((x>>3)&1); }
constexpr int idx_of(int m){ int r=-1; for(int i=0;i<16;i++) if(MASKS[i]==m) r=i; return r; }
struct GPTab {
  int cnt[16];
  signed char ii[16][16];
  signed char jj[16][16];
  float ss[16][16];
};
constexpr GPTab make_gptab(){
  GPTab t{};
  for(int i=0;i<16;i++) for(int j=0;j<16;j++){
    int a=MASKS[i], b=MASKS[j];
    if((a&b&1)!=0) continue;           // e0^2 = 0 kills the term
    int sw=0;
    for(int bi=0;bi<4;bi++) if((b>>bi)&1) sw += popc4(a>>(bi+1));
    int k = idx_of(a^b);
    int c = t.cnt[k];
    t.ii[k][c]=(signed char)i; t.jj[k][c]=(signed char)j;
    t.ss[k][c]=(sw&1)? -1.0f : 1.0f;
    t.cnt[k]=c+1;
  }
  return t;
}
} // namespace ga

__device__ const ga::GPTab GPT = ga::make_gptab();
__constant__ int GRADE16[16] = {0,1,1,1,1,2,2,2,2,2,2,3,3,3,3,4};
// blades with INNER==1: idx {0,2,3,4,7,9,10,14} -> mask 0x469D; compressed pos:
__constant__ int CPOS16[16] = {0,-1,1,2,3,-1,-1,4,-1,5,6,-1,-1,-1,7,-1};

#define NTOK 16384   // B*N
#define NSEQ 4096
#define NB 4
#define QP 48        // q/k padded feature dim (40 real + 8 zero), bf16 hi/lo
#define VTROWS 80    // v tile rows (feats)
#define NW 8         // waves per attention block (key-split factor)

// --------------------------------------------------------------------------
// K1: h[token][o][c] = equi_linear(mv, w_in); mv sparse.
// --------------------------------------------------------------------------
__global__ __launch_bounds__(256) void k_init_h(
    const float* __restrict__ x, const float* __restrict__ w_in,
    float* __restrict__ h)
{
  int gid = blockIdx.x*256 + threadIdx.x;      // token*5 + o
  if (gid >= NTOK*5) return;
  int o = gid % 5, token = gid / 5;
  const float* xt = x + (size_t)token*35;
  const float* w0 = w_in + o*32;               // grade-0 block, row o
  float s = w0[0];                             // mv[0][0] = 1.0
  #pragma unroll
  for (int i=1;i<32;i++) s += w0[i]*xt[i];
  float w2c = w_in[2*160 + o*32 + 0];          // grade-2, input channel 0
  float* ht = h + (size_t)token*80 + o*16;
  #pragma unroll
  for (int c=0;c<16;c++) ht[c] = 0.f;
  ht[0] = s;
  ht[5] = w2c*xt[32];
  ht[6] = w2c*xt[33];
  ht[8] = w2c*xt[34];
}

// --------------------------------------------------------------------------
// K2: fused equi_layernorm + q,k,v equi_linear -> bf16 hi/lo staging.
// q/k: [token][48] (40 real feats + 8 zero), q pre-scaled.
// v: TILE-MAJOR vt[b][tile=n/32][feat(80)][n&31], hi/lo buffers.
// --------------------------------------------------------------------------
__global__ __launch_bounds__(256) void k_ln_qkv(
    const float* __restrict__ h,
    const float* __restrict__ wq, const float* __restrict__ wk,
    const float* __restrict__ wv,
    __hip_bfloat16* __restrict__ qh, __hip_bfloat16* __restrict__ ql,
    __hip_bfloat16* __restrict__ kh, __hip_bfloat16* __restrict__ kl,
    __hip_bfloat16* __restrict__ vh, __hip_bfloat16* __restrict__ vl)
{
  int tid = threadIdx.x;
  int c   = tid & 15;
  int token = blockIdx.x*16 + (tid>>4);
  int b = token >> 12;          // /4096
  int n = token & 4095;
  int vt_tile = b*128 + (n>>5);
  int vt_col  = n & 31;
  const float* ht = h + (size_t)token*80;
  float hv[5];
  #pragma unroll
  for (int i=0;i<5;i++) hv[i] = ht[i*16 + c];
  bool inner = (0x469D >> c) & 1;
  float part = 0.f;
  if (inner) {
    #pragma unroll
    for (int i=0;i<5;i++) part += hv[i]*hv[i];
  }
  part += __shfl_xor(part, 1);
  part += __shfl_xor(part, 2);
  part += __shfl_xor(part, 4);
  part += __shfl_xor(part, 8);
  float denom = sqrtf(part*(1.f/80.f) + 1e-6f);
  float rinv = 1.f/denom;
  float rln[5];
  #pragma unroll
  for (int i=0;i<5;i++) rln[i] = hv[i]*rinv;

  int g = GRADE16[c];
  int cp = CPOS16[c];
  const float scale = 0.11180339887498949f;    // 1/sqrt(16*5)
  #pragma unroll
  for (int o=0;o<5;o++) {
    const float* wqr = wq + g*25 + o*5;
    const float* wkr = wk + g*25 + o*5;
    const float* wvr = wv + g*25 + o*5;
    float aq=0.f, ak=0.f, av=0.f;
    #pragma unroll
    for (int i=0;i<5;i++) {
      aq += rln[i]*wqr[i];
      ak += rln[i]*wkr[i];
      av += rln[i]*wvr[i];
    }
    __hip_bfloat16 vhi = __float2bfloat16(av);
    size_t vo = ((size_t)vt_tile*VTROWS + o*16 + c)*32 + vt_col;
    vh[vo] = vhi;
    vl[vo] = __float2bfloat16(av - __bfloat162float(vhi));
    if (inner) {
      float aqs = aq*scale;
      __hip_bfloat16 qhi = __float2bfloat16(aqs);
      __hip_bfloat16 khi = __float2bfloat16(ak);
      size_t qo = (size_t)token*QP + o*8 + cp;
      qh[qo] = qhi;  ql[qo] = __float2bfloat16(aqs - __bfloat162float(qhi));
      kh[qo] = khi;  kl[qo] = __float2bfloat16(ak  - __bfloat162float(khi));
    }
  }
  // zero pads: feats 40..47
  if (c < 8) {
    size_t po = (size_t)token*QP + 40 + c;
    __hip_bfloat16 z = __float2bfloat16(0.f);
    qh[po]=z; ql[po]=z; kh[po]=z; kl[po]=z;
  }
}

// --------------------------------------------------------------------------
// K3: MFMA flash attention, hi/lo split, 8-way intra-block key-split with
// LDS merge, fused epilogue (normalize + wo projection + residual).
// Block = 512 thr = 8 waves, one 32-row Q-tile; wave w covers keys
// [w*512, w*512+512). Swapped QK^T: S = mfma(A=K, B=Q) -> C col = q-row.
// --------------------------------------------------------------------------
__global__ __launch_bounds__(512, 4) void k_attn_mfma(
    const __hip_bfloat16* __restrict__ qh, const __hip_bfloat16* __restrict__ ql,
    const __hip_bfloat16* __restrict__ kh, const __hip_bfloat16* __restrict__ kl,
    const __hip_bfloat16* __restrict__ vh, const __hip_bfloat16* __restrict__ vl,
    const float* __restrict__ wo, float* __restrict__ h)
{
  __shared__ __align__(16) float satt[32][80];
  __shared__ __align__(16) float ldsb[NW][32];
  __shared__ __align__(16) float sM[NW][32];
  __shared__ __align__(16) float sL[NW][32];
  __shared__ __align__(16) float sMax[32];
  __shared__ __align__(16) float sInv[32];
  __shared__ float sWo[125];
  int tid = threadIdx.x;
  int w  = tid >> 6;
  int ln = tid & 31;
  int hf = (tid >> 5) & 1;
  int b  = blockIdx.y;
  int rowbase = b*NSEQ + blockIdx.x*32;

  for (int i=tid; i<125; i+=512) sWo[i] = wo[i];
  for (int i=tid; i<2560; i+=512) ((float*)satt)[i] = 0.f;

  // Q frags (B operand): B[k][j]: j=lane&31=qrow, k=(lane>>5)*8+e
  const __hip_bfloat16* qhp = qh + (size_t)(rowbase + ln)*QP + hf*8;
  const __hip_bfloat16* qlp = ql + (size_t)(rowbase + ln)*QP + hf*8;
  bf16x8 qh0 = *(const bf16x8*)(qhp);
  bf16x8 qh1 = *(const bf16x8*)(qhp + 16);
  bf16x8 qh2 = *(const bf16x8*)(qhp + 32);
  bf16x8 ql0 = *(const bf16x8*)(qlp);
  bf16x8 ql1 = *(const bf16x8*)(qlp + 16);
  bf16x8 ql2 = *(const bf16x8*)(qlp + 32);

  f32x16 acc0, acc1, acc2;
  #pragma unroll
  for (int r=0;r<16;r++){ acc0[r]=0.f; acc1[r]=0.f; acc2[r]=0.f; }
  float m = -1e30f, lsum = 0.f;

  // per-lane offsets into a V tile (tile-major: [feat(80)][32 keys])
  int voff0 = (     ln)*32 + hf*8;
  int voff1 = (32 + ln)*32 + hf*8;
  int voff2 = (64 + (ln&15))*32 + hf*8;   // feats 64..79; cols>=16 duplicated

  int kbeg = w*(NSEQ/NW), kend = kbeg + NSEQ/NW;
  for (int koff=kbeg; koff<kend; koff+=32) {
    // K frags (A operand): A[i][k]: i=lane&31=key, k=(lane>>5)*8+e
    const __hip_bfloat16* khp = kh + (size_t)(b*NSEQ + koff + ln)*QP + hf*8;
    const __hip_bfloat16* klp = kl + (size_t)(b*NSEQ + koff + ln)*QP + hf*8;
    bf16x8 kh0 = *(const bf16x8*)(khp);
    bf16x8 kh1 = *(const bf16x8*)(khp + 16);
    bf16x8 kh2 = *(const bf16x8*)(khp + 32);
    bf16x8 kl0 = *(const bf16x8*)(klp);
    bf16x8 kl1 = *(const bf16x8*)(klp + 16);
    bf16x8 kl2 = *(const bf16x8*)(klp + 32);
    f32x16 S;
    #pragma unroll
    for (int r=0;r<16;r++) S[r]=0.f;
    S = __builtin_amdgcn_mfma_f32_32x32x16_bf16(kh0, qh0, S, 0,0,0);
    S = __builtin_amdgcn_mfma_f32_32x32x16_bf16(kh1, qh1, S, 0,0,0);
    S = __builtin_amdgcn_mfma_f32_32x32x16_bf16(kh2, qh2, S, 0,0,0);
    S = __builtin_amdgcn_mfma_f32_32x32x16_bf16(kh0, ql0, S, 0,0,0);
    S = __builtin_amdgcn_mfma_f32_32x32x16_bf16(kh1, ql1, S, 0,0,0);
    S = __builtin_amdgcn_mfma_f32_32x32x16_bf16(kh2, ql2, S, 0,0,0);
    S = __builtin_amdgcn_mfma_f32_32x32x16_bf16(kl0, qh0, S, 0,0,0);
    S = __builtin_amdgcn_mfma_f32_32x32x16_bf16(kl1, qh1, S, 0,0,0);
    S = __builtin_amdgcn_mfma_f32_32x32x16_bf16(kl2, qh2, S, 0,0,0);
    // S frag: lane holds q-row (ln); 16 keys: key(r) = (r&3)+8*(r>>2)+4*hf

    // tile max: balanced tree
    float t01 = fmaxf(S[0],S[1]),   t23 = fmaxf(S[2],S[3]);
    float t45 = fmaxf(S[4],S[5]),   t67 = fmaxf(S[6],S[7]);
    float t89 = fmaxf(S[8],S[9]),   tab = fmaxf(S[10],S[11]);
    float tcd = fmaxf(S[12],S[13]), tef = fmaxf(S[14],S[15]);
    float q0 = fmaxf(t01,t23), q1 = fmaxf(t45,t67);
    float q2 = fmaxf(t89,tab), q3 = fmaxf(tcd,tef);
    float tmax = fmaxf(fmaxf(q0,q1), fmaxf(q2,q3));
    tmax = fmaxf(tmax, __shfl_xor(tmax, 32));
    if (!__all(tmax <= m + 8.f)) {
      float mn = fmaxf(m, tmax);
      float f = __expf(m - mn);
      if (hf==0) ldsb[w][ln] = f;
      float fv[16];
      *(float4*)&fv[0]  = *(const float4*)&ldsb[w][ 0 + hf*4];
      *(float4*)&fv[4]  = *(const float4*)&ldsb[w][ 8 + hf*4];
      *(float4*)&fv[8]  = *(const float4*)&ldsb[w][16 + hf*4];
      *(float4*)&fv[12] = *(const float4*)&ldsb[w][24 + hf*4];
      #pragma unroll
      for (int r=0;r<16;r++){ float fr=fv[r]; acc0[r]*=fr; acc1[r]*=fr; acc2[r]*=fr; }
      lsum *= f;
      m = mn;
    }
    float p[16];
    #pragma unroll
    for (int r=0;r<16;r++) p[r] = __expf(S[r] - m);
    float ls = 0.f;
    #pragma unroll
    for (int r=0;r<16;r++) ls += p[r];
    ls += __shfl_xor(ls, 32);
    lsum += ls;

    // split P -> hi/lo packed pairs via TRUNCATION (lo = exact remainder)
    unsigned hbp[8], lbp[8];
    #pragma unroll
    for (int e=0;e<8;e++) {
      unsigned u0 = __float_as_uint(p[2*e]), u1 = __float_as_uint(p[2*e+1]);
      unsigned h0f = u0 & 0xFFFF0000u, h1f = u1 & 0xFFFF0000u;
      hbp[e] = (u0>>16) | h1f;
      float l0 = p[2*e]   - __uint_as_float(h0f);
      float l1 = p[2*e+1] - __uint_as_float(h1f);
      lbp[e] = (__float_as_uint(l0)>>16) | (__float_as_uint(l1) & 0xFFFF0000u);
    }
    // exchange halves: A0 covers keys 0..15, A1 keys 16..31
    union { unsigned u[4]; bf16x8 v; } A0h, A1h, A0l, A1l;
    {
      unsigned sa = hf ? hbp[0] : hbp[2], sb = hf ? hbp[1] : hbp[3];
      unsigned ra = __shfl_xor((int)sa,32), rb = __shfl_xor((int)sb,32);
      unsigned sc = hf ? hbp[4] : hbp[6], sd = hf ? hbp[5] : hbp[7];
      unsigned rc = __shfl_xor((int)sc,32), rd = __shfl_xor((int)sd,32);
      A0h.u[0] = hf ? ra     : hbp[0];  A0h.u[1] = hf ? rb     : hbp[1];
      A0h.u[2] = hf ? hbp[2] : ra;      A0h.u[3] = hf ? hbp[3] : rb;
      A1h.u[0] = hf ? rc     : hbp[4];  A1h.u[1] = hf ? rd     : hbp[5];
      A1h.u[2] = hf ? hbp[6] : rc;      A1h.u[3] = hf ? hbp[7] : rd;
    }
    {
      unsigned sa = hf ? lbp[0] : lbp[2], sb = hf ? lbp[1] : lbp[3];
      unsigned ra = __shfl_xor((int)sa,32), rb = __shfl_xor((int)sb,32);
      unsigned sc = hf ? lbp[4] : lbp[6], sd = hf ? lbp[5] : lbp[7];
      unsigned rc = __shfl_xor((int)sc,32), rd = __shfl_xor((int)sd,32);
      A0l.u[0] = hf ? ra     : lbp[0];  A0l.u[1] = hf ? rb     : lbp[1];
      A0l.u[2] = hf ? lbp[2] : ra;      A0l.u[3] = hf ? lbp[3] : rb;
      A1l.u[0] = hf ? rc     : lbp[4];  A1l.u[1] = hf ? rd     : lbp[5];
      A1l.u[2] = hf ? lbp[6] : rc;      A1l.u[3] = hf ? lbp[7] : rd;
    }

    // V frags from tile-major layout: B[k][j]: j=lane&31=feat, k=key
    const __hip_bfloat16* vtbh = vh + (size_t)(b*128 + (koff>>5))*(VTROWS*32);
    const __hip_bfloat16* vtbl = vl + (size_t)(b*128 + (koff>>5))*(VTROWS*32);
    bf16x8 Bh00 = *(const bf16x8*)(vtbh + voff0);
    bf16x8 Bh01 = *(const bf16x8*)(vtbh + voff0 + 16);
    bf16x8 Bh10 = *(const bf16x8*)(vtbh + voff1);
    bf16x8 Bh11 = *(const bf16x8*)(vtbh + voff1 + 16);
    bf16x8 Bh20 = *(const bf16x8*)(vtbh + voff2);
    bf16x8 Bh21 = *(const bf16x8*)(vtbh + voff2 + 16);
    bf16x8 Bl00 = *(const bf16x8*)(vtbl + voff0);
    bf16x8 Bl01 = *(const bf16x8*)(vtbl + voff0 + 16);
    bf16x8 Bl10 = *(const bf16x8*)(vtbl + voff1);
    bf16x8 Bl11 = *(const bf16x8*)(vtbl + voff1 + 16);
    bf16x8 Bl20 = *(const bf16x8*)(vtbl + voff2);
    bf16x8 Bl21 = *(const bf16x8*)(vtbl + voff2 + 16);

    acc0 = __builtin_amdgcn_mfma_f32_32x32x16_bf16(A0h.v, Bh00, acc0, 0,0,0);
    acc0 = __builtin_amdgcn_mfma_f32_32x32x16_bf16(A1h.v, Bh01, acc0, 0,0,0);
    acc0 = __builtin_amdgcn_mfma_f32_32x32x16_bf16(A0h.v, Bl00, acc0, 0,0,0);
    acc0 = __builtin_amdgcn_mfma_f32_32x32x16_bf16(A1h.v, Bl01, acc0, 0,0,0);
    acc0 = __builtin_amdgcn_mfma_f32_32x32x16_bf16(A0l.v, Bh00, acc0, 0,0,0);
    acc0 = __builtin_amdgcn_mfma_f32_32x32x16_bf16(A1l.v, Bh01, acc0, 0,0,0);

    acc1 = __builtin_amdgcn_mfma_f32_32x32x16_bf16(A0h.v, Bh10, acc1, 0,0,0);
    acc1 = __builtin_amdgcn_mfma_f32_32x32x16_bf16(A1h.v, Bh11, acc1, 0,0,0);
    acc1 = __builtin_amdgcn_mfma_f32_32x32x16_bf16(A0h.v, Bl10, acc1, 0,0,0);
    acc1 = __builtin_amdgcn_mfma_f32_32x32x16_bf16(A1h.v, Bl11, acc1, 0,0,0);
    acc1 = __builtin_amdgcn_mfma_f32_32x32x16_bf16(A0l.v, Bh10, acc1, 0,0,0);
    acc1 = __builtin_amdgcn_mfma_f32_32x32x16_bf16(A1l.v, Bh11, acc1, 0,0,0);

    acc2 = __builtin_amdgcn_mfma_f32_32x32x16_bf16(A0h.v, Bh20, acc2, 0,0,0);
    acc2 = __builtin_amdgcn_mfma_f32_32x32x16_bf16(A1h.v, Bh21, acc2, 0,0,0);
    acc2 = __builtin_amdgcn_mfma_f32_32x32x16_bf16(A0h.v, Bl20, acc2, 0,0,0);
    acc2 = __builtin_amdgcn_mfma_f32_32x32x16_bf16(A1h.v, Bl21, acc2, 0,0,0);
    acc2 = __builtin_amdgcn_mfma_f32_32x32x16_bf16(A0l.v, Bh20, acc2, 0,0,0);
    acc2 = __builtin_amdgcn_mfma_f32_32x32x16_bf16(A1l.v, Bh21, acc2, 0,0,0);
  }

  // ---- cross-wave merge ----
  if (hf==0) { sM[w][ln] = m; sL[w][ln] = lsum; }
  __syncthreads();
  if (tid < 32) {
    float M = sM[0][tid];
    #pragma unroll
    for (int u=1;u<NW;u++) M = fmaxf(M, sM[u][tid]);
    float L = 0.f;
    #pragma unroll
    for (int u=0;u<NW;u++) L += __expf(sM[u][tid] - M)*sL[u][tid];
    sMax[tid] = M;
    sInv[tid] = 1.f/L;
  }
  __syncthreads();
  // per-wave scale factor in C-frag row layout, accumulate into satt
  {
    float sm[16], sx[16];
    *(float4*)&sm[0]  = *(const float4*)&sM[w][ 0 + hf*4];
    *(float4*)&sm[4]  = *(const float4*)&sM[w][ 8 + hf*4];
    *(float4*)&sm[8]  = *(const float4*)&sM[w][16 + hf*4];
    *(float4*)&sm[12] = *(const float4*)&sM[w][24 + hf*4];
    *(float4*)&sx[0]  = *(const float4*)&sMax[ 0 + hf*4];
    *(float4*)&sx[4]  = *(const float4*)&sMax[ 8 + hf*4];
    *(float4*)&sx[8]  = *(const float4*)&sMax[16 + hf*4];
    *(float4*)&sx[12] = *(const float4*)&sMax[24 + hf*4];
    #pragma unroll
    for (int r=0;r<16;r++) {
      int row = (r&3) + 8*(r>>2) + 4*hf;
      float f = __expf(sm[r] - sx[r]);
      atomicAdd(&satt[row][ln],    f*acc0[r]);
      atomicAdd(&satt[row][32+ln], f*acc1[r]);
      if (ln < 16) atomicAdd(&satt[row][64+ln], f*acc2[r]);
    }
  }
  __syncthreads();
  // wo-projection + residual: h[rowbase*80 + flat] += proj
  float* hb = h + (size_t)rowbase*80;
  #pragma unroll
  for (int e=0;e<5;e++) {
    int flat = e*512 + tid;
    int rr = flat/80, oc = flat - rr*80;
    int o = oc>>4, c = oc&15;
    int g = GRADE16[c];
    const float* wor = sWo + g*25 + o*5;
    float a = 0.f;
    #pragma unroll
    for (int i=0;i<5;i++) a += satt[rr][i*16+c]*wor[i];
    hb[flat] += a*sInv[rr];
  }
}

// --------------------------------------------------------------------------
// K4: fused equi_layernorm + MLP (w1 -> geometric product -> gated gelu ->
// w2) + residual. 16 threads/token (one per output blade), 16 tokens/block.
// --------------------------------------------------------------------------
__global__ __launch_bounds__(256) void k_mlp(
    float* __restrict__ h,
    const float* __restrict__ w1, const float* __restrict__ w2)
{
  __shared__ float sh1[16][10][16];
  int tid = threadIdx.x;
  int c   = tid & 15;
  int tl  = tid >> 4;
  int token = blockIdx.x*16 + tl;
  float* ht = h + (size_t)token*80;
  float hv[5];
  #pragma unroll
  for (int i=0;i<5;i++) hv[i] = ht[i*16 + c];
  bool inner = (0x469D >> c) & 1;
  float part = 0.f;
  if (inner) {
    #pragma unroll
    for (int i=0;i<5;i++) part += hv[i]*hv[i];
  }
  part += __shfl_xor(part, 1);
  part += __shfl_xor(part, 2);
  part += __shfl_xor(part, 4);
  part += __shfl_xor(part, 8);
  float denom = sqrtf(part*(1.f/80.f) + 1e-6f);
  float rinv = 1.f/denom;
  float rln[5];
  #pragma unroll
  for (int i=0;i<5;i++) rln[i] = hv[i]*rinv;

  int g = GRADE16[c];
  #pragma unroll
  for (int o=0;o<10;o++) {
    const float* w1r = w1 + g*50 + o*5;
    float a=0.f;
    #pragma unroll
    for (int i=0;i<5;i++) a += rln[i]*w1r[i];
    sh1[tl][o][c] = a;
  }
  __syncthreads();
  // geometric product: thread c computes gp[hh][c] for all 5 channels
  float gpv[5];
  #pragma unroll
  for (int hh=0; hh<5; hh++) {
    float a = 0.f;
    int n = GPT.cnt[c];
    for (int e=0; e<n; ++e) {
      a += GPT.ss[c][e]*sh1[tl][hh][GPT.ii[c][e]]*sh1[tl][5+hh][GPT.jj[c][e]];
    }
    gpv[hh] = a;
  }
  // gate by gelu(scalar component) -- lane c=0 of this token's 16-lane group
  int base = (tid & 63) & ~15;
  #pragma unroll
  for (int hh=0;hh<5;hh++) {
    float g0 = __shfl(gpv[hh], base);
    float u  = 0.7978845608028654f*(g0 + 0.044715f*g0*g0*g0);
    float gate = 0.5f*g0*(1.f + tanhf(u));
    gpv[hh] *= gate;
  }
  // final equi_linear (w2) + residual
  #pragma unroll
  for (int o=0;o<5;o++) {
    const float* w2r = w2 + g*25 + o*5;
    float a=0.f;
    #pragma unroll
    for (int i=0;i<5;i++) a += gpv[i]*w2r[i];
    ht[o*16+c] += a;
  }
}

// --------------------------------------------------------------------------
// K5: final equi_linear (w_out) + output extraction.
// --------------------------------------------------------------------------
__global__ __launch_bounds__(256) void k_out(
    const float* __restrict__ h, const float* __restrict__ w_out,
    float* __restrict__ out)
{
  int gid = blockIdx.x*256 + threadIdx.x;
  if (gid >= NTOK*35) return;
  int j = gid % 35, token = gid / 35;
  const float* ht = h + (size_t)token*80;
  float a = 0.f;
  if (j < 32) {
    const float* w = w_out + j*5;              // grade 0, row j
    #pragma unroll
    for (int i=0;i<5;i++) a += ht[i*16 + 0]*w[i];
  } else {
    int c = (j==32)?5:((j==33)?6:8);
    const float* w = w_out + 2*160 + 0*5;      // grade 2, row 0
    #pragma unroll
    for (int i=0;i<5;i++) a += ht[i*16 + c]*w[i];
  }
  out[gid] = a;
}

// --------------------------------------------------------------------------
extern "C" void kernel_launch(void* const* d_in, const int* in_sizes, int n_in,
                              void* d_out, int out_size, void* d_ws, size_t ws_size,
                              hipStream_t stream) {
  const float* x     = (const float*)d_in[0];
  const float* w_in  = (const float*)d_in[1];
  const float* w_out = (const float*)d_in[2];
  const float* wq    = (const float*)d_in[3];
  const float* wk    = (const float*)d_in[4];
  const float* wv    = (const float*)d_in[5];
  const float* wo    = (const float*)d_in[6];
  const float* w1    = (const float*)d_in[7];
  const float* w2    = (const float*)d_in[8];
  float* out = (float*)d_out;

  // workspace carve: h(fp32) + ql,kh,kl(48 bf16/token) + vh,vl(tiled 80x32)
  // = 15,204,352 B. q_hi lives in d_out (1.57MB <= 2.29MB, dead until k_out).
  char* p = (char*)d_ws;
  float* h = (float*)p;                      p += (size_t)NTOK*80*4;
  __hip_bfloat16* ql = (__hip_bfloat16*)p;   p += (size_t)NTOK*QP*2;
  __hip_bfloat16* kh = (__hip_bfloat16*)p;   p += (size_t)NTOK*QP*2;
  __hip_bfloat16* kl = (__hip_bfloat16*)p;   p += (size_t)NTOK*QP*2;
  __hip_bfloat16* vh = (__hip_bfloat16*)p;   p += (size_t)NB*128*VTROWS*32*2;
  __hip_bfloat16* vl = (__hip_bfloat16*)p;
  __hip_bfloat16* qh = (__hip_bfloat16*)d_out;

  k_init_h<<<(NTOK*5 + 255)/256, 256, 0, stream>>>(x, w_in, h);
  for (int blk=0; blk<3; ++blk) {
    k_ln_qkv<<<NTOK/16, 256, 0, stream>>>(h, wq+blk*125, wk+blk*125, wv+blk*125,
                                          qh, ql, kh, kl, vh, vl);
    k_attn_mfma<<<dim3(NSEQ/32, NB), 512, 0, stream>>>(qh, ql, kh, kl, vh, vl,
                                                       wo+blk*125, h);
    k_mlp<<<NTOK/16, 256, 0, stream>>>(h, w1+blk*250, w2+blk*125);
  }
  k_out<<<(NTOK*35 + 255)/256, 256, 0, stream>>>(h, w_out, out);
}

// Round 7
// 452.354 us; speedup vs baseline: 6.9420x; 1.2040x over previous
//
#include <hip/hip_runtime.h>
#include <hip/hip_bf16.h>
#include <math.h>

typedef __attribute__((ext_vector_type(8)))  _Float16 f16x8;
typedef __attribute__((ext_vector_type(2)))  __fp16   fp16v2;
typedef __attribute__((ext_vector_type(16))) float    f32x16;

// ---------------------------------------------------------------------------
// GATr forward on MI355X. B=4, N=4096, H=5, BLK=3, INV=32, 16 blades.
// Metric (0,1,1,1) PGA. Blade order sorted by (grade, mask).
// Attention: single-pass fp16 MFMA (11-bit mantissa suffices), exp2-domain
// softmax, K-prefetch + early-V for latency hiding, 8-way key-split.
// ---------------------------------------------------------------------------

namespace ga {
constexpr int MASKS[16] = {0,1,2,4,8,3,5,6,9,10,12,7,11,13,14,15};
constexpr int popc4(int x){ return (x&1)+((x>>1)&1)+((x>>2)&1)+((x>>3)&1); }
constexpr int idx_of(int m){ int r=-1; for(int i=0;i<16;i++) if(MASKS[i]==m) r=i; return r; }
struct GPTab {
  int cnt[16];
  signed char ii[16][16];
  signed char jj[16][16];
  float ss[16][16];
};
constexpr GPTab make_gptab(){
  GPTab t{};
  for(int i=0;i<16;i++) for(int j=0;j<16;j++){
    int a=MASKS[i], b=MASKS[j];
    if((a&b&1)!=0) continue;           // e0^2 = 0 kills the term
    int sw=0;
    for(int bi=0;bi<4;bi++) if((b>>bi)&1) sw += popc4(a>>(bi+1));
    int k = idx_of(a^b);
    int c = t.cnt[k];
    t.ii[k][c]=(signed char)i; t.jj[k][c]=(signed char)j;
    t.ss[k][c]=(sw&1)? -1.0f : 1.0f;
    t.cnt[k]=c+1;
  }
  return t;
}
} // namespace ga

__device__ const ga::GPTab GPT = ga::make_gptab();
__constant__ int GRADE16[16] = {0,1,1,1,1,2,2,2,2,2,2,3,3,3,3,4};
// blades with INNER==1: idx {0,2,3,4,7,9,10,14} -> mask 0x469D; compressed pos:
__constant__ int CPOS16[16] = {0,-1,1,2,3,-1,-1,4,-1,5,6,-1,-1,-1,7,-1};

#define NTOK 16384   // B*N
#define NSEQ 4096
#define NB 4
#define QP 48        // q/k padded feature dim (40 real + 8 zero), fp16
#define VTROWS 80    // v tile rows (feats)
#define NW 8         // waves per attention block (key-split factor)
#define THR2 11.54f  // defer-max threshold in log2 domain (= 8 nats)

// --------------------------------------------------------------------------
// K1: h[token][o][c] = equi_linear(mv, w_in); mv sparse.
// --------------------------------------------------------------------------
__global__ __launch_bounds__(256) void k_init_h(
    const float* __restrict__ x, const float* __restrict__ w_in,
    float* __restrict__ h)
{
  int gid = blockIdx.x*256 + threadIdx.x;      // token*5 + o
  if (gid >= NTOK*5) return;
  int o = gid % 5, token = gid / 5;
  const float* xt = x + (size_t)token*35;
  const float* w0 = w_in + o*32;               // grade-0 block, row o
  float s = w0[0];                             // mv[0][0] = 1.0
  #pragma unroll
  for (int i=1;i<32;i++) s += w0[i]*xt[i];
  float w2c = w_in[2*160 + o*32 + 0];          // grade-2, input channel 0
  float* ht = h + (size_t)token*80 + o*16;
  #pragma unroll
  for (int c=0;c<16;c++) ht[c] = 0.f;
  ht[0] = s;
  ht[5] = w2c*xt[32];
  ht[6] = w2c*xt[33];
  ht[8] = w2c*xt[34];
}

// --------------------------------------------------------------------------
// K2: fused equi_layernorm + q,k,v equi_linear -> fp16 staging.
// q/k: [token][48] (40 real feats + 8 zero); q pre-scaled by scale*log2(e).
// v: TILE-MAJOR vt[b][tile=n/32][feat(80)][n&31].
// --------------------------------------------------------------------------
__global__ __launch_bounds__(256) void k_ln_qkv(
    const float* __restrict__ h,
    const float* __restrict__ wq, const float* __restrict__ wk,
    const float* __restrict__ wv,
    _Float16* __restrict__ qf, _Float16* __restrict__ kf,
    _Float16* __restrict__ vf)
{
  int tid = threadIdx.x;
  int c   = tid & 15;
  int token = blockIdx.x*16 + (tid>>4);
  int b = token >> 12;          // /4096
  int n = token & 4095;
  int vt_tile = b*128 + (n>>5);
  int vt_col  = n & 31;
  const float* ht = h + (size_t)token*80;
  float hv[5];
  #pragma unroll
  for (int i=0;i<5;i++) hv[i] = ht[i*16 + c];
  bool inner = (0x469D >> c) & 1;
  float part = 0.f;
  if (inner) {
    #pragma unroll
    for (int i=0;i<5;i++) part += hv[i]*hv[i];
  }
  part += __shfl_xor(part, 1);
  part += __shfl_xor(part, 2);
  part += __shfl_xor(part, 4);
  part += __shfl_xor(part, 8);
  float denom = sqrtf(part*(1.f/80.f) + 1e-6f);
  float rinv = 1.f/denom;
  float rln[5];
  #pragma unroll
  for (int i=0;i<5;i++) rln[i] = hv[i]*rinv;

  int g = GRADE16[c];
  int cp = CPOS16[c];
  // (1/sqrt(16*5)) * log2(e): logits land in log2 domain -> exp2 softmax
  const float scaleq = 0.16129820906f;
  #pragma unroll
  for (int o=0;o<5;o++) {
    const float* wqr = wq + g*25 + o*5;
    const float* wkr = wk + g*25 + o*5;
    const float* wvr = wv + g*25 + o*5;
    float aq=0.f, ak=0.f, av=0.f;
    #pragma unroll
    for (int i=0;i<5;i++) {
      aq += rln[i]*wqr[i];
      ak += rln[i]*wkr[i];
      av += rln[i]*wvr[i];
    }
    vf[((size_t)vt_tile*VTROWS + o*16 + c)*32 + vt_col] = (_Float16)av;
    if (inner) {
      size_t qo = (size_t)token*QP + o*8 + cp;
      qf[qo] = (_Float16)(aq*scaleq);
      kf[qo] = (_Float16)ak;
    }
  }
  // zero pads: feats 40..47
  if (c < 8) {
    size_t po = (size_t)token*QP + 40 + c;
    qf[po] = (_Float16)0.f;
    kf[po] = (_Float16)0.f;
  }
}

// --------------------------------------------------------------------------
// K3: fp16 MFMA flash attention, 8-way intra-block key-split with LDS merge,
// fused epilogue (normalize + wo projection + residual). Block = 512 thr =
// 8 waves, one 32-row Q-tile; wave w covers keys [w*512, (w+1)*512).
// Swapped QK^T: S = mfma(A=K, B=Q) -> C col (lane&31) = q-row.
// Softmax in exp2 domain (q pre-scaled by log2 e).
// --------------------------------------------------------------------------
__global__ __launch_bounds__(512, 4) void k_attn_mfma(
    const _Float16* __restrict__ qf, const _Float16* __restrict__ kf,
    const _Float16* __restrict__ vf,
    const float* __restrict__ wo, float* __restrict__ h)
{
  __shared__ __align__(16) float satt[32][80];
  __shared__ __align__(16) float ldsb[NW][32];
  __shared__ __align__(16) float sM[NW][32];
  __shared__ __align__(16) float sL[NW][32];
  __shared__ __align__(16) float sMax[32];
  __shared__ __align__(16) float sInv[32];
  __shared__ float sWo[125];
  int tid = threadIdx.x;
  int w  = tid >> 6;
  int ln = tid & 31;
  int hf = (tid >> 5) & 1;
  int b  = blockIdx.y;
  int rowbase = b*NSEQ + blockIdx.x*32;

  for (int i=tid; i<125; i+=512) sWo[i] = wo[i];
  for (int i=tid; i<2560; i+=512) ((float*)satt)[i] = 0.f;

  // Q frags (B operand): B[k][j]: j=lane&31=qrow, k=(lane>>5)*8+e
  const _Float16* qp = qf + (size_t)(rowbase + ln)*QP + hf*8;
  f16x8 q0 = *(const f16x8*)(qp);
  f16x8 q1 = *(const f16x8*)(qp + 16);
  f16x8 q2 = *(const f16x8*)(qp + 32);

  f32x16 acc0, acc1, acc2;
  #pragma unroll
  for (int r=0;r<16;r++){ acc0[r]=0.f; acc1[r]=0.f; acc2[r]=0.f; }
  float m = -1e30f, lsum = 0.f;

  // per-lane offsets into a V tile (tile-major: [feat(80)][32 keys])
  int voff0 = (     ln)*32 + hf*8;
  int voff1 = (32 + ln)*32 + hf*8;
  int voff2 = (64 + (ln&15))*32 + hf*8;   // feats 64..79; cols>=16 duplicated

  int kbeg = w*(NSEQ/NW), kend = kbeg + NSEQ/NW;
  const _Float16* kbase = kf + (size_t)(b*NSEQ + ln)*QP + hf*8;

  // prologue: preload first K tile
  const _Float16* kp0 = kbase + (size_t)kbeg*QP;
  f16x8 kc0 = *(const f16x8*)(kp0);
  f16x8 kc1 = *(const f16x8*)(kp0 + 16);
  f16x8 kc2 = *(const f16x8*)(kp0 + 32);

  for (int koff=kbeg; koff<kend; koff+=32) {
    // QK^T on prefetched K frags: A[i][k]: i=key, k=feat
    f32x16 S;
    #pragma unroll
    for (int r=0;r<16;r++) S[r]=0.f;
    S = __builtin_amdgcn_mfma_f32_32x32x16_f16(kc0, q0, S, 0,0,0);
    S = __builtin_amdgcn_mfma_f32_32x32x16_f16(kc1, q1, S, 0,0,0);
    S = __builtin_amdgcn_mfma_f32_32x32x16_f16(kc2, q2, S, 0,0,0);
    // S frag: lane holds q-row (ln); 16 keys: key(r) = (r&3)+8*(r>>2)+4*hf

    // prefetch next K tile (wraps to kbeg on last iter; harmless dup)
    int knext = koff + 32; if (knext >= kend) knext = kbeg;
    const _Float16* kp = kbase + (size_t)knext*QP;
    f16x8 kn0 = *(const f16x8*)(kp);
    f16x8 kn1 = *(const f16x8*)(kp + 16);
    f16x8 kn2 = *(const f16x8*)(kp + 32);

    // V loads for current tile (issued before softmax; consumed after)
    const _Float16* vtb = vf + (size_t)(b*128 + (koff>>5))*(VTROWS*32);
    f16x8 Bv00 = *(const f16x8*)(vtb + voff0);
    f16x8 Bv01 = *(const f16x8*)(vtb + voff0 + 16);
    f16x8 Bv10 = *(const f16x8*)(vtb + voff1);
    f16x8 Bv11 = *(const f16x8*)(vtb + voff1 + 16);
    f16x8 Bv20 = *(const f16x8*)(vtb + voff2);
    f16x8 Bv21 = *(const f16x8*)(vtb + voff2 + 16);

    // tile max: balanced tree (log2-domain logits)
    float t01 = fmaxf(S[0],S[1]),   t23 = fmaxf(S[2],S[3]);
    float t45 = fmaxf(S[4],S[5]),   t67 = fmaxf(S[6],S[7]);
    float t89 = fmaxf(S[8],S[9]),   tab = fmaxf(S[10],S[11]);
    float tcd = fmaxf(S[12],S[13]), tef = fmaxf(S[14],S[15]);
    float u0 = fmaxf(t01,t23), u1 = fmaxf(t45,t67);
    float u2 = fmaxf(t89,tab), u3 = fmaxf(tcd,tef);
    float tmax = fmaxf(fmaxf(u0,u1), fmaxf(u2,u3));
    tmax = fmaxf(tmax, __shfl_xor(tmax, 32));
    if (!__all(tmax <= m + THR2)) {
      float mn = fmaxf(m, tmax);
      float f = exp2f(m - mn);
      if (hf==0) ldsb[w][ln] = f;
      float fv[16];
      *(float4*)&fv[0]  = *(const float4*)&ldsb[w][ 0 + hf*4];
      *(float4*)&fv[4]  = *(const float4*)&ldsb[w][ 8 + hf*4];
      *(float4*)&fv[8]  = *(const float4*)&ldsb[w][16 + hf*4];
      *(float4*)&fv[12] = *(const float4*)&ldsb[w][24 + hf*4];
      #pragma unroll
      for (int r=0;r<16;r++){ float fr=fv[r]; acc0[r]*=fr; acc1[r]*=fr; acc2[r]*=fr; }
      lsum *= f;
      m = mn;
    }
    float p[16];
    #pragma unroll
    for (int r=0;r<16;r++) p[r] = exp2f(S[r] - m);
    float ls = 0.f;
    #pragma unroll
    for (int r=0;r<16;r++) ls += p[r];
    ls += __shfl_xor(ls, 32);
    lsum += ls;

    // pack P -> fp16 pairs; key-order pairs (p[2e],p[2e+1])
    unsigned pk[8];
    #pragma unroll
    for (int e=0;e<8;e++) {
      union { fp16v2 h2; unsigned u; } cv;
      cv.h2 = __builtin_amdgcn_cvt_pkrtz(p[2*e], p[2*e+1]);
      pk[e] = cv.u;
    }
    // exchange halves: A0 covers keys 0..15, A1 keys 16..31
    union { unsigned u[4]; f16x8 v; } A0, A1;
    {
      unsigned sa = hf ? pk[0] : pk[2], sb = hf ? pk[1] : pk[3];
      unsigned ra = __shfl_xor((int)sa,32), rb = __shfl_xor((int)sb,32);
      unsigned sc = hf ? pk[4] : pk[6], sd = hf ? pk[5] : pk[7];
      unsigned rc = __shfl_xor((int)sc,32), rd = __shfl_xor((int)sd,32);
      A0.u[0] = hf ? ra    : pk[0];  A0.u[1] = hf ? rb    : pk[1];
      A0.u[2] = hf ? pk[2] : ra;     A0.u[3] = hf ? pk[3] : rb;
      A1.u[0] = hf ? rc    : pk[4];  A1.u[1] = hf ? rd    : pk[5];
      A1.u[2] = hf ? pk[6] : rc;     A1.u[3] = hf ? pk[7] : rd;
    }

    // PV: B[k][j]: j=lane&31=feat(in 32-block), k=(lane>>5)*8+e=key
    acc0 = __builtin_amdgcn_mfma_f32_32x32x16_f16(A0.v, Bv00, acc0, 0,0,0);
    acc0 = __builtin_amdgcn_mfma_f32_32x32x16_f16(A1.v, Bv01, acc0, 0,0,0);
    acc1 = __builtin_amdgcn_mfma_f32_32x32x16_f16(A0.v, Bv10, acc1, 0,0,0);
    acc1 = __builtin_amdgcn_mfma_f32_32x32x16_f16(A1.v, Bv11, acc1, 0,0,0);
    acc2 = __builtin_amdgcn_mfma_f32_32x32x16_f16(A0.v, Bv20, acc2, 0,0,0);
    acc2 = __builtin_amdgcn_mfma_f32_32x32x16_f16(A1.v, Bv21, acc2, 0,0,0);

    kc0 = kn0; kc1 = kn1; kc2 = kn2;
  }

  // ---- cross-wave merge ----
  if (hf==0) { sM[w][ln] = m; sL[w][ln] = lsum; }
  __syncthreads();
  if (tid < 32) {
    float M = sM[0][tid];
    #pragma unroll
    for (int u=1;u<NW;u++) M = fmaxf(M, sM[u][tid]);
    float L = 0.f;
    #pragma unroll
    for (int u=0;u<NW;u++) L += exp2f(sM[u][tid] - M)*sL[u][tid];
    sMax[tid] = M;
    sInv[tid] = 1.f/L;
  }
  __syncthreads();
  // per-wave scale factor in C-frag row layout, accumulate into satt
  {
    float sm[16], sx[16];
    *(float4*)&sm[0]  = *(const float4*)&sM[w][ 0 + hf*4];
    *(float4*)&sm[4]  = *(const float4*)&sM[w][ 8 + hf*4];
    *(float4*)&sm[8]  = *(const float4*)&sM[w][16 + hf*4];
    *(float4*)&sm[12] = *(const float4*)&sM[w][24 + hf*4];
    *(float4*)&sx[0]  = *(const float4*)&sMax[ 0 + hf*4];
    *(float4*)&sx[4]  = *(const float4*)&sMax[ 8 + hf*4];
    *(float4*)&sx[8]  = *(const float4*)&sMax[16 + hf*4];
    *(float4*)&sx[12] = *(const float4*)&sMax[24 + hf*4];
    #pragma unroll
    for (int r=0;r<16;r++) {
      int row = (r&3) + 8*(r>>2) + 4*hf;
      float f = exp2f(sm[r] - sx[r]);
      atomicAdd(&satt[row][ln],    f*acc0[r]);
      atomicAdd(&satt[row][32+ln], f*acc1[r]);
      if (ln < 16) atomicAdd(&satt[row][64+ln], f*acc2[r]);
    }
  }
  __syncthreads();
  // wo-projection + residual: h[rowbase*80 + flat] += proj
  float* hb = h + (size_t)rowbase*80;
  #pragma unroll
  for (int e=0;e<5;e++) {
    int flat = e*512 + tid;
    int rr = flat/80, oc = flat - rr*80;
    int o = oc>>4, c = oc&15;
    int g = GRADE16[c];
    const float* wor = sWo + g*25 + o*5;
    float a = 0.f;
    #pragma unroll
    for (int i=0;i<5;i++) a += satt[rr][i*16+c]*wor[i];
    hb[flat] += a*sInv[rr];
  }
}

// --------------------------------------------------------------------------
// K4: fused equi_layernorm + MLP (w1 -> geometric product -> gated gelu ->
// w2) + residual. 16 threads/token (one per output blade), 16 tokens/block.
// --------------------------------------------------------------------------
__global__ __launch_bounds__(256) void k_mlp(
    float* __restrict__ h,
    const float* __restrict__ w1, const float* __restrict__ w2)
{
  __shared__ float sh1[16][10][16];
  int tid = threadIdx.x;
  int c   = tid & 15;
  int tl  = tid >> 4;
  int token = blockIdx.x*16 + tl;
  float* ht = h + (size_t)token*80;
  float hv[5];
  #pragma unroll
  for (int i=0;i<5;i++) hv[i] = ht[i*16 + c];
  bool inner = (0x469D >> c) & 1;
  float part = 0.f;
  if (inner) {
    #pragma unroll
    for (int i=0;i<5;i++) part += hv[i]*hv[i];
  }
  part += __shfl_xor(part, 1);
  part += __shfl_xor(part, 2);
  part += __shfl_xor(part, 4);
  part += __shfl_xor(part, 8);
  float denom = sqrtf(part*(1.f/80.f) + 1e-6f);
  float rinv = 1.f/denom;
  float rln[5];
  #pragma unroll
  for (int i=0;i<5;i++) rln[i] = hv[i]*rinv;

  int g = GRADE16[c];
  #pragma unroll
  for (int o=0;o<10;o++) {
    const float* w1r = w1 + g*50 + o*5;
    float a=0.f;
    #pragma unroll
    for (int i=0;i<5;i++) a += rln[i]*w1r[i];
    sh1[tl][o][c] = a;
  }
  __syncthreads();
  // geometric product: thread c computes gp[hh][c] for all 5 channels
  float gpv[5];
  #pragma unroll
  for (int hh=0; hh<5; hh++) {
    float a = 0.f;
    int n = GPT.cnt[c];
    for (int e=0; e<n; ++e) {
      a += GPT.ss[c][e]*sh1[tl][hh][GPT.ii[c][e]]*sh1[tl][5+hh][GPT.jj[c][e]];
    }
    gpv[hh] = a;
  }
  // gate by gelu(scalar component) -- lane c=0 of this token's 16-lane group
  int base = (tid & 63) & ~15;
  #pragma unroll
  for (int hh=0;hh<5;hh++) {
    float g0 = __shfl(gpv[hh], base);
    float u  = 0.7978845608028654f*(g0 + 0.044715f*g0*g0*g0);
    float gate = 0.5f*g0*(1.f + tanhf(u));
    gpv[hh] *= gate;
  }
  // final equi_linear (w2) + residual
  #pragma unroll
  for (int o=0;o<5;o++) {
    const float* w2r = w2 + g*25 + o*5;
    float a=0.f;
    #pragma unroll
    for (int i=0;i<5;i++) a += gpv[i]*w2r[i];
    ht[o*16+c] += a;
  }
}

// --------------------------------------------------------------------------
// K5: final equi_linear (w_out) + output extraction.
// --------------------------------------------------------------------------
__global__ __launch_bounds__(256) void k_out(
    const float* __restrict__ h, const float* __restrict__ w_out,
    float* __restrict__ out)
{
  int gid = blockIdx.x*256 + threadIdx.x;
  if (gid >= NTOK*35) return;
  int j = gid % 35, token = gid / 35;
  const float* ht = h + (size_t)token*80;
  float a = 0.f;
  if (j < 32) {
    const float* w = w_out + j*5;              // grade 0, row j
    #pragma unroll
    for (int i=0;i<5;i++) a += ht[i*16 + 0]*w[i];
  } else {
    int c = (j==32)?5:((j==33)?6:8);
    const float* w = w_out + 2*160 + 0*5;      // grade 2, row 0
    #pragma unroll
    for (int i=0;i<5;i++) a += ht[i*16 + c]*w[i];
  }
  out[gid] = a;
}

// --------------------------------------------------------------------------
extern "C" void kernel_launch(void* const* d_in, const int* in_sizes, int n_in,
                              void* d_out, int out_size, void* d_ws, size_t ws_size,
                              hipStream_t stream) {
  const float* x     = (const float*)d_in[0];
  const float* w_in  = (const float*)d_in[1];
  const float* w_out = (const float*)d_in[2];
  const float* wq    = (const float*)d_in[3];
  const float* wk    = (const float*)d_in[4];
  const float* wv    = (const float*)d_in[5];
  const float* wo    = (const float*)d_in[6];
  const float* w1    = (const float*)d_in[7];
  const float* w2    = (const float*)d_in[8];
  float* out = (float*)d_out;

  // workspace carve: h fp32 (5.24MB) + qf,kf fp16 (1.57MB each) +
  // vf fp16 tiled (2.62MB)  => ~11MB total.
  char* p = (char*)d_ws;
  float* h = (float*)p;              p += (size_t)NTOK*80*4;
  _Float16* qf = (_Float16*)p;       p += (size_t)NTOK*QP*2;
  _Float16* kf = (_Float16*)p;       p += (size_t)NTOK*QP*2;
  _Float16* vf = (_Float16*)p;

  k_init_h<<<(NTOK*5 + 255)/256, 256, 0, stream>>>(x, w_in, h);
  for (int blk=0; blk<3; ++blk) {
    k_ln_qkv<<<NTOK/16, 256, 0, stream>>>(h, wq+blk*125, wk+blk*125, wv+blk*125,
                                          qf, kf, vf);
    k_attn_mfma<<<dim3(NSEQ/32, NB), 512, 0, stream>>>(qf, kf, vf,
                                                       wo+blk*125, h);
    k_mlp<<<NTOK/16, 256, 0, stream>>>(h, w1+blk*250, w2+blk*125);
  }
  k_out<<<(NTOK*35 + 255)/256, 256, 0, stream>>>(h, w_out, out);
}